// Round 2
// baseline (312.368 us; speedup 1.0000x reference)
//
#include <hip/hip_runtime.h>
#include <stdint.h>

// ---------------- Threefry-2x32-20 (exact JAX semantics) ----------------
__device__ __forceinline__ uint32_t rotl32(uint32_t v, int d) { return (v << d) | (v >> (32 - d)); }

__device__ __forceinline__ void threefry2x32(uint32_t k0, uint32_t k1, uint32_t& x0, uint32_t& x1) {
  const uint32_t ks2 = k0 ^ k1 ^ 0x1BD11BDAu;
  x0 += k0; x1 += k1;
  x0 += x1; x1 = rotl32(x1, 13); x1 ^= x0;
  x0 += x1; x1 = rotl32(x1, 15); x1 ^= x0;
  x0 += x1; x1 = rotl32(x1, 26); x1 ^= x0;
  x0 += x1; x1 = rotl32(x1, 6);  x1 ^= x0;
  x0 += k1; x1 += ks2 + 1u;
  x0 += x1; x1 = rotl32(x1, 17); x1 ^= x0;
  x0 += x1; x1 = rotl32(x1, 29); x1 ^= x0;
  x0 += x1; x1 = rotl32(x1, 16); x1 ^= x0;
  x0 += x1; x1 = rotl32(x1, 24); x1 ^= x0;
  x0 += ks2; x1 += k0 + 2u;
  x0 += x1; x1 = rotl32(x1, 13); x1 ^= x0;
  x0 += x1; x1 = rotl32(x1, 15); x1 ^= x0;
  x0 += x1; x1 = rotl32(x1, 26); x1 ^= x0;
  x0 += x1; x1 = rotl32(x1, 6);  x1 ^= x0;
  x0 += k0; x1 += k1 + 3u;
  x0 += x1; x1 = rotl32(x1, 17); x1 ^= x0;
  x0 += x1; x1 = rotl32(x1, 29); x1 ^= x0;
  x0 += x1; x1 = rotl32(x1, 16); x1 ^= x0;
  x0 += x1; x1 = rotl32(x1, 24); x1 ^= x0;
  x0 += k1; x1 += ks2 + 4u;
  x0 += x1; x1 = rotl32(x1, 13); x1 ^= x0;
  x0 += x1; x1 = rotl32(x1, 15); x1 ^= x0;
  x0 += x1; x1 = rotl32(x1, 26); x1 ^= x0;
  x0 += x1; x1 = rotl32(x1, 6);  x1 ^= x0;
  x0 += ks2; x1 += k0 + 5u;
}

// ---------------- fp32 tiled GEMM, 64x64 tile, BK=32 ----------------
// EPI 0: relu(x + bias)   EPI 1: sigmoid(x + bias)
template <int EPI>
__global__ __launch_bounds__(256) void gemm_tile(const float* __restrict__ A,
                                                 const float* __restrict__ Bm,
                                                 const float* __restrict__ bias,
                                                 float* __restrict__ C,
                                                 int M, int N, int K) {
  __shared__ float As[64][33];
  __shared__ float Bs[32][68];
  const int tid = threadIdx.x;
  const int bm = blockIdx.y * 64, bn = blockIdx.x * 64;
  const int tx = tid & 15, ty = tid >> 4;
  const int tx4 = tx * 4, ty4 = ty * 4;
  float acc[4][4] = {{0.f}};

  for (int k0 = 0; k0 < K; k0 += 32) {
#pragma unroll
    for (int j = 0; j < 2; ++j) {
      const int f = tid + 256 * j;          // 0..511 float4 slots (64 rows x 8)
      const int row = f >> 3, kk = (f & 7) << 2;
      const float4 v = *reinterpret_cast<const float4*>(&A[(size_t)(bm + row) * K + k0 + kk]);
      As[row][kk] = v.x; As[row][kk + 1] = v.y; As[row][kk + 2] = v.z; As[row][kk + 3] = v.w;
    }
#pragma unroll
    for (int j = 0; j < 2; ++j) {
      const int f = tid + 256 * j;          // 0..511 float4 slots (32 rows x 16)
      const int row = f >> 4, nn = (f & 15) << 2;
      const float4 v = *reinterpret_cast<const float4*>(&Bm[(size_t)(k0 + row) * N + bn + nn]);
      *reinterpret_cast<float4*>(&Bs[row][nn]) = v;
    }
    __syncthreads();
#pragma unroll
    for (int k = 0; k < 32; ++k) {
      const float a0 = As[ty4 + 0][k], a1 = As[ty4 + 1][k], a2 = As[ty4 + 2][k], a3 = As[ty4 + 3][k];
      const float4 b4 = *reinterpret_cast<const float4*>(&Bs[k][tx4]);
      acc[0][0] = fmaf(a0, b4.x, acc[0][0]); acc[0][1] = fmaf(a0, b4.y, acc[0][1]);
      acc[0][2] = fmaf(a0, b4.z, acc[0][2]); acc[0][3] = fmaf(a0, b4.w, acc[0][3]);
      acc[1][0] = fmaf(a1, b4.x, acc[1][0]); acc[1][1] = fmaf(a1, b4.y, acc[1][1]);
      acc[1][2] = fmaf(a1, b4.z, acc[1][2]); acc[1][3] = fmaf(a1, b4.w, acc[1][3]);
      acc[2][0] = fmaf(a2, b4.x, acc[2][0]); acc[2][1] = fmaf(a2, b4.y, acc[2][1]);
      acc[2][2] = fmaf(a2, b4.z, acc[2][2]); acc[2][3] = fmaf(a2, b4.w, acc[2][3]);
      acc[3][0] = fmaf(a3, b4.x, acc[3][0]); acc[3][1] = fmaf(a3, b4.y, acc[3][1]);
      acc[3][2] = fmaf(a3, b4.z, acc[3][2]); acc[3][3] = fmaf(a3, b4.w, acc[3][3]);
    }
    __syncthreads();
  }

  const float4 bb = *reinterpret_cast<const float4*>(&bias[bn + tx4]);
#pragma unroll
  for (int i = 0; i < 4; ++i) {
    float4 o;
    o.x = acc[i][0] + bb.x; o.y = acc[i][1] + bb.y; o.z = acc[i][2] + bb.z; o.w = acc[i][3] + bb.w;
    if (EPI == 0) {
      o.x = fmaxf(o.x, 0.f); o.y = fmaxf(o.y, 0.f); o.z = fmaxf(o.z, 0.f); o.w = fmaxf(o.w, 0.f);
    } else {
      o.x = 1.f / (1.f + expf(-o.x)); o.y = 1.f / (1.f + expf(-o.y));
      o.z = 1.f / (1.f + expf(-o.z)); o.w = 1.f / (1.f + expf(-o.w));
    }
    *reinterpret_cast<float4*>(&C[(size_t)(bm + ty4 + i) * N + bn + tx4]) = o;
  }
}

// ---------------- threshold = sigmoid(h @ Wt + bt), one wave per row ----------------
__global__ __launch_bounds__(256) void thresh_kernel(const float* __restrict__ h,
                                                     const float* __restrict__ Wt,
                                                     const float* __restrict__ bt,
                                                     float* __restrict__ out, int B) {
  const int lane = threadIdx.x & 63;
  const int row = blockIdx.x * 4 + (threadIdx.x >> 6);
  if (row >= B) return;
  const float* hr = h + (size_t)row * 1024;
  float s = 0.f;
#pragma unroll
  for (int it = 0; it < 4; ++it) {
    const int k = (lane + it * 64) * 4;
    const float4 a = *reinterpret_cast<const float4*>(&hr[k]);
    const float4 w = *reinterpret_cast<const float4*>(&Wt[k]);
    s += a.x * w.x + a.y * w.y + a.z * w.z + a.w * w.w;
  }
#pragma unroll
  for (int off = 32; off; off >>= 1) s += __shfl_xor(s, off);
  if (lane == 0) out[row] = 1.f / (1.f + expf(-(s + bt[0])));
}

// ---------------- program decode: bit2dec of P_* per (b,t), and prog_len per b ----------------
__global__ __launch_bounds__(256) void decode_prog(const float* __restrict__ P_op,
                                                   const float* __restrict__ P_dst,
                                                   const float* __restrict__ P_s1,
                                                   const float* __restrict__ P_s2,
                                                   const float* __restrict__ P_imm,
                                                   const float* __restrict__ Plen,
                                                   float* __restrict__ prog,
                                                   float* __restrict__ plen, int BT) {
  const int i = blockIdx.x * 256 + threadIdx.x;
  if (i >= BT) return;
  const float* po = P_op + (size_t)i * 4;
  const float op = po[0] + 2.f * po[1] + 4.f * po[2] + 8.f * po[3];
  const float* pd = P_dst + (size_t)i * 3;
  const float dv = pd[0] + 2.f * pd[1] + 4.f * pd[2];
  const float* p1 = P_s1 + (size_t)i * 3;
  const float s1v = p1[0] + 2.f * p1[1] + 4.f * p1[2];
  const float* p2 = P_s2 + (size_t)i * 3;
  const float s2v = p2[0] + 2.f * p2[1] + 4.f * p2[2];
  const float* pi = P_imm + (size_t)i * 3;
  const float imv = pi[0] + 2.f * pi[1] + 4.f * pi[2];
  float* o = prog + (size_t)i * 5;
  o[0] = op; o[1] = dv; o[2] = s1v; o[3] = s2v; o[4] = imv;
  if ((i & 15) == 0) {
    const int b = i >> 4;
    const float* pl = Plen + (size_t)b * 4;
    plen[b] = pl[0] + 2.f * pl[1] + 4.f * pl[2] + 8.f * pl[3];
  }
}

// ---------------- per-(b,g) soft-VM scan, 16 steps, all state in registers ----------------
__global__ __launch_bounds__(256) void scan_kernel(const float* __restrict__ Rbits,
                                                   const float* __restrict__ prog,
                                                   const float* __restrict__ plen,
                                                   float* __restrict__ Rfinal, int B) {
  __shared__ float s_bits[16][128];
  __shared__ float s_prog[16][80];
  __shared__ float s_plen[16];
  const int tid = threadIdx.x;
  const int b0 = blockIdx.x * 16;
#pragma unroll
  for (int j = 0; j < 8; ++j) {
    const int f = tid + 256 * j;  // 0..2047
    s_bits[f >> 7][f & 127] = Rbits[(size_t)(b0 + (f >> 7)) * 128 + (f & 127)];
  }
#pragma unroll
  for (int j = 0; j < 5; ++j) {
    const int f = tid + 256 * j;  // 0..1279
    s_prog[f / 80][f % 80] = prog[(size_t)b0 * 80 + f];
  }
  if (tid < 16) s_plen[tid] = plen[b0 + tid];
  __syncthreads();

  const int lb = tid >> 4, g = tid & 15;
  const int bg = (b0 + lb) * 16 + g;

  // ---- JAX threefry with jax_threefry_partitionable=True (default in modern JAX) ----
  // split(key(42), 2) is fold-like: keys[i] = full (y0,y1) of threefry((0,42), (0,i)).
  // randint's multiplier (2^16 % 128)^2 % 128 == 0, so idx = lower_bits % 128, where
  // lower_bits = random_bits(k2=keys[1], 32, shape): per flat element n,
  // (b1,b2) = threefry(k2, (n>>32, n&0xffffffff)) and bits = b1 ^ b2 (32-bit fold).
  uint32_t k2a, k2b;
  { uint32_t x0 = 0u, x1 = 1u; threefry2x32(0u, 42u, x0, x1); k2a = x0; k2b = x1; }
  uint32_t p0, p1;
  {
    uint32_t x0 = 0u, x1 = (uint32_t)bg * 2u;
    threefry2x32(k2a, k2b, x0, x1);
    p0 = (x0 ^ x1) & 127u;
  }
  {
    uint32_t x0 = 0u, x1 = (uint32_t)bg * 2u + 1u;
    threefry2x32(k2a, k2b, x0, x1);
    p1 = (x0 ^ x1) & 127u;
  }

  float R[8], M[8];
#pragma unroll
  for (int r = 0; r < 8; ++r) {
    float a = 0.f;
#pragma unroll
    for (int bit = 0; bit < 16; ++bit) {
      const int pos = r * 16 + bit;
      float v = s_bits[lb][pos];
      const bool flip = (g != 0) && ((int)p0 == pos || (int)p1 == pos);
      v = flip ? 1.0f - v : v;
      a = fmaf(v, (float)(1 << bit), a);
    }
    R[r] = a;
    M[r] = 0.f;
  }

  const float pl = s_plen[lb];
  for (int t = 0; t < 16; ++t) {
    const float op = s_prog[lb][t * 5 + 0];
    const float dst = s_prog[lb][t * 5 + 1];
    const float sa = s_prog[lb][t * 5 + 2];
    const float sb = s_prog[lb][t * 5 + 3];
    const float imm = s_prog[lb][t * 5 + 4];
    const float active = fminf(fmaxf(pl - (float)t, 0.f), 1.f);
    float r1 = 0.f, r2 = 0.f, m1 = 0.f, old = 0.f;
    float wd[8];
#pragma unroll
    for (int i = 0; i < 8; ++i) {
      const float w1 = fmaxf(1.f - fabsf(sa - (float)i), 0.f);
      const float w2 = fmaxf(1.f - fabsf(sb - (float)i), 0.f);
      wd[i] = fmaxf(1.f - fabsf(dst - (float)i), 0.f);
      r1 = fmaf(w1, R[i], r1);
      r2 = fmaf(w2, R[i], r2);
      m1 = fmaf(w1, M[i], m1);
      old = fmaf(wd[i], R[i], old);
    }
    float results[16];
    results[0] = old;               results[1] = r1 + r2;
    results[2] = r1 - r2;           results[3] = r1 * r2 * (1.f / 65536.f);
    results[4] = r1;                results[5] = imm;
    results[6] = r1 + imm;          results[7] = fmaxf(r1, r2);
    results[8] = fminf(r1, r2);     results[9] = -r1;
    results[10] = 0.5f * r1;        results[11] = r2;
    results[12] = m1;               results[13] = old;
    results[14] = fabsf(r1);        results[15] = old;
    float res = 0.f;
    const float pstore = fmaxf(1.f - fabsf(op - 13.f), 0.f);
#pragma unroll
    for (int o = 0; o < 16; ++o) res = fmaf(fmaxf(1.f - fabsf(op - (float)o), 0.f), results[o], res);
#pragma unroll
    for (int i = 0; i < 8; ++i) {
      R[i] = fmaf(active * wd[i], res - R[i], R[i]);
      M[i] = fmaf(active * pstore * wd[i], r1 - M[i], M[i]);
    }
  }

  float* outp = Rfinal + (size_t)bg * 8;
#pragma unroll
  for (int r = 0; r < 8; ++r) outp[r] = R[r];
}

// ---------------- reg_hidden = LN(R @ W_r2h + b) * g + b ; one wave per (b,g) ----------------
__global__ __launch_bounds__(256) void final_expand(const float* __restrict__ Rf,
                                                    const float* __restrict__ W,
                                                    const float* __restrict__ bias,
                                                    const float* __restrict__ gam,
                                                    const float* __restrict__ bet,
                                                    float* __restrict__ out) {
  const int lane = threadIdx.x & 63;
  const int bg = blockIdx.x * 4 + (threadIdx.x >> 6);
  const float* Rp = Rf + (size_t)bg * 8;
  float r[8];
#pragma unroll
  for (int i = 0; i < 8; ++i) r[i] = Rp[i];
  const int h0 = lane * 8;
  float x[8];
#pragma unroll
  for (int j = 0; j < 8; ++j) x[j] = bias[h0 + j];
#pragma unroll
  for (int reg = 0; reg < 8; ++reg) {
    const float4 wa = *reinterpret_cast<const float4*>(&W[reg * 512 + h0]);
    const float4 wb = *reinterpret_cast<const float4*>(&W[reg * 512 + h0 + 4]);
    x[0] = fmaf(r[reg], wa.x, x[0]); x[1] = fmaf(r[reg], wa.y, x[1]);
    x[2] = fmaf(r[reg], wa.z, x[2]); x[3] = fmaf(r[reg], wa.w, x[3]);
    x[4] = fmaf(r[reg], wb.x, x[4]); x[5] = fmaf(r[reg], wb.y, x[5]);
    x[6] = fmaf(r[reg], wb.z, x[6]); x[7] = fmaf(r[reg], wb.w, x[7]);
  }
  float s1 = 0.f, s2 = 0.f;
#pragma unroll
  for (int j = 0; j < 8; ++j) { s1 += x[j]; s2 = fmaf(x[j], x[j], s2); }
#pragma unroll
  for (int off = 32; off; off >>= 1) { s1 += __shfl_xor(s1, off); s2 += __shfl_xor(s2, off); }
  const float mean = s1 * (1.f / 512.f);
  const float var = s2 * (1.f / 512.f) - mean * mean;
  const float inv = rsqrtf(var + 1e-5f);
  float y[8];
#pragma unroll
  for (int j = 0; j < 8; ++j) y[j] = (x[j] - mean) * inv * gam[h0 + j] + bet[h0 + j];
  float* dst = out + (size_t)bg * 512 + h0;
  *reinterpret_cast<float4*>(dst) = make_float4(y[0], y[1], y[2], y[3]);
  *reinterpret_cast<float4*>(dst + 4) = make_float4(y[4], y[5], y[6], y[7]);
}

// ---------------- launch ----------------
extern "C" void kernel_launch(void* const* d_in, const int* in_sizes, int n_in,
                              void* d_out, int out_size, void* d_ws, size_t ws_size,
                              hipStream_t stream) {
  const float* z    = (const float*)d_in[0];
  const float* P_op = (const float*)d_in[1];
  const float* P_dst= (const float*)d_in[2];
  const float* P_s1 = (const float*)d_in[3];
  const float* P_s2 = (const float*)d_in[4];
  const float* P_imm= (const float*)d_in[5];
  const float* Plen = (const float*)d_in[6];
  // d_in[7] = group_num (=16, fixed by setup)
  const float* W1   = (const float*)d_in[8];
  const float* b1   = (const float*)d_in[9];
  const float* WR   = (const float*)d_in[10];
  const float* bR   = (const float*)d_in[11];
  const float* Wt   = (const float*)d_in[12];
  const float* bt   = (const float*)d_in[13];
  const float* W_r2h= (const float*)d_in[14];
  const float* b_r2h= (const float*)d_in[15];
  const float* ln_g = (const float*)d_in[16];
  const float* ln_b = (const float*)d_in[17];

  const int B = in_sizes[0] / 512;  // 8192
  float* out = (float*)d_out;
  float* h = out;                                  // B*1024 f32 staged in d_out; consumed
  float* thr_out = out + (size_t)B * 16 * 512;     // threshold output region

  float* ws = (float*)d_ws;                        // ~11 MB used
  float* Rbits  = ws;                              // B*128
  float* prog   = Rbits + (size_t)B * 128;         // B*16*5
  float* plen   = prog + (size_t)B * 80;           // B
  float* Rfinal = plen + B;                        // B*16*8

  const dim3 blk(256);
  gemm_tile<0><<<dim3(1024 / 64, B / 64), blk, 0, stream>>>(z, W1, b1, h, B, 1024, 512);
  gemm_tile<1><<<dim3(128 / 64, B / 64), blk, 0, stream>>>(h, WR, bR, Rbits, B, 128, 1024);
  thresh_kernel<<<dim3(B / 4), blk, 0, stream>>>(h, Wt, bt, thr_out, B);
  decode_prog<<<dim3((B * 16 + 255) / 256), blk, 0, stream>>>(P_op, P_dst, P_s1, P_s2, P_imm,
                                                              Plen, prog, plen, B * 16);
  scan_kernel<<<dim3(B / 16), blk, 0, stream>>>(Rbits, prog, plen, Rfinal, B);
  final_expand<<<dim3(B * 16 / 4), blk, 0, stream>>>(Rfinal, W_r2h, b_r2h, ln_g, ln_b, out);
}

// Round 3
// 293.974 us; speedup vs baseline: 1.0626x; 1.0626x over previous
//
#include <hip/hip_runtime.h>
#include <stdint.h>

// ---------------- Threefry-2x32-20 (exact JAX partitionable semantics) ----------------
__device__ __forceinline__ uint32_t rotl32(uint32_t v, int d) { return (v << d) | (v >> (32 - d)); }

__device__ __forceinline__ void threefry2x32(uint32_t k0, uint32_t k1, uint32_t& x0, uint32_t& x1) {
  const uint32_t ks2 = k0 ^ k1 ^ 0x1BD11BDAu;
  x0 += k0; x1 += k1;
  x0 += x1; x1 = rotl32(x1, 13); x1 ^= x0;
  x0 += x1; x1 = rotl32(x1, 15); x1 ^= x0;
  x0 += x1; x1 = rotl32(x1, 26); x1 ^= x0;
  x0 += x1; x1 = rotl32(x1, 6);  x1 ^= x0;
  x0 += k1; x1 += ks2 + 1u;
  x0 += x1; x1 = rotl32(x1, 17); x1 ^= x0;
  x0 += x1; x1 = rotl32(x1, 29); x1 ^= x0;
  x0 += x1; x1 = rotl32(x1, 16); x1 ^= x0;
  x0 += x1; x1 = rotl32(x1, 24); x1 ^= x0;
  x0 += ks2; x1 += k0 + 2u;
  x0 += x1; x1 = rotl32(x1, 13); x1 ^= x0;
  x0 += x1; x1 = rotl32(x1, 15); x1 ^= x0;
  x0 += x1; x1 = rotl32(x1, 26); x1 ^= x0;
  x0 += x1; x1 = rotl32(x1, 6);  x1 ^= x0;
  x0 += k0; x1 += k1 + 3u;
  x0 += x1; x1 = rotl32(x1, 17); x1 ^= x0;
  x0 += x1; x1 = rotl32(x1, 29); x1 ^= x0;
  x0 += x1; x1 = rotl32(x1, 16); x1 ^= x0;
  x0 += x1; x1 = rotl32(x1, 24); x1 ^= x0;
  x0 += k1; x1 += ks2 + 4u;
  x0 += x1; x1 = rotl32(x1, 13); x1 ^= x0;
  x0 += x1; x1 = rotl32(x1, 15); x1 ^= x0;
  x0 += x1; x1 = rotl32(x1, 26); x1 ^= x0;
  x0 += x1; x1 = rotl32(x1, 6);  x1 ^= x0;
  x0 += ks2; x1 += k0 + 5u;
}

// ---------------- fp32 tiled GEMM, 64x64 tile, BK=32, A transposed in LDS ----------------
// EPI 0: relu(x + bias)   EPI 2: none (partial accumulation; blockIdx.z selects K-slice)
template <int EPI>
__global__ __launch_bounds__(256) void gemm64(const float* __restrict__ A,
                                              const float* __restrict__ Bm,
                                              const float* __restrict__ bias,
                                              float* __restrict__ C,
                                              int N, int K, int kSplit, size_t mnStride) {
  __shared__ float At[32][68];   // At[k][m] (row stride 272B: 16B-aligned, 2-way-free reads)
  __shared__ float Bs[32][68];
  const int tid = threadIdx.x;
  const int bm = blockIdx.y * 64, bn = blockIdx.x * 64;
  const int tx = tid & 15, ty = tid >> 4;
  const int tx4 = tx * 4, ty4 = ty * 4;
  const int k_lo = blockIdx.z * kSplit, k_hi = k_lo + kSplit;
  float acc[4][4] = {{0.f}};

  for (int k0 = k_lo; k0 < k_hi; k0 += 32) {
#pragma unroll
    for (int j = 0; j < 2; ++j) {
      const int f = tid + 256 * j;          // 512 float4 slots (64 rows x 8)
      const int row = f >> 3, kk = (f & 7) << 2;
      const float4 v = *reinterpret_cast<const float4*>(&A[(size_t)(bm + row) * K + k0 + kk]);
      At[kk + 0][row] = v.x; At[kk + 1][row] = v.y;
      At[kk + 2][row] = v.z; At[kk + 3][row] = v.w;
    }
#pragma unroll
    for (int j = 0; j < 2; ++j) {
      const int f = tid + 256 * j;          // 512 float4 slots (32 rows x 16)
      const int row = f >> 4, nn = (f & 15) << 2;
      const float4 v = *reinterpret_cast<const float4*>(&Bm[(size_t)(k0 + row) * N + bn + nn]);
      *reinterpret_cast<float4*>(&Bs[row][nn]) = v;
    }
    __syncthreads();
#pragma unroll
    for (int k = 0; k < 32; ++k) {
      const float4 a4 = *reinterpret_cast<const float4*>(&At[k][ty4]);
      const float4 b4 = *reinterpret_cast<const float4*>(&Bs[k][tx4]);
      acc[0][0] = fmaf(a4.x, b4.x, acc[0][0]); acc[0][1] = fmaf(a4.x, b4.y, acc[0][1]);
      acc[0][2] = fmaf(a4.x, b4.z, acc[0][2]); acc[0][3] = fmaf(a4.x, b4.w, acc[0][3]);
      acc[1][0] = fmaf(a4.y, b4.x, acc[1][0]); acc[1][1] = fmaf(a4.y, b4.y, acc[1][1]);
      acc[1][2] = fmaf(a4.y, b4.z, acc[1][2]); acc[1][3] = fmaf(a4.y, b4.w, acc[1][3]);
      acc[2][0] = fmaf(a4.z, b4.x, acc[2][0]); acc[2][1] = fmaf(a4.z, b4.y, acc[2][1]);
      acc[2][2] = fmaf(a4.z, b4.z, acc[2][2]); acc[2][3] = fmaf(a4.z, b4.w, acc[2][3]);
      acc[3][0] = fmaf(a4.w, b4.x, acc[3][0]); acc[3][1] = fmaf(a4.w, b4.y, acc[3][1]);
      acc[3][2] = fmaf(a4.w, b4.z, acc[3][2]); acc[3][3] = fmaf(a4.w, b4.w, acc[3][3]);
    }
    __syncthreads();
  }

  float* Cp = C + (size_t)blockIdx.z * mnStride;
  if (EPI == 0) {
    const float4 bb = *reinterpret_cast<const float4*>(&bias[bn + tx4]);
#pragma unroll
    for (int i = 0; i < 4; ++i) {
      float4 o;
      o.x = fmaxf(acc[i][0] + bb.x, 0.f); o.y = fmaxf(acc[i][1] + bb.y, 0.f);
      o.z = fmaxf(acc[i][2] + bb.z, 0.f); o.w = fmaxf(acc[i][3] + bb.w, 0.f);
      *reinterpret_cast<float4*>(&Cp[(size_t)(bm + ty4 + i) * N + bn + tx4]) = o;
    }
  } else {
#pragma unroll
    for (int i = 0; i < 4; ++i) {
      float4 o = make_float4(acc[i][0], acc[i][1], acc[i][2], acc[i][3]);
      *reinterpret_cast<float4*>(&Cp[(size_t)(bm + ty4 + i) * N + bn + tx4]) = o;
    }
  }
}

// ---------------- sum 4 K-split partials + bias -> sigmoid -> Rbits ----------------
__global__ __launch_bounds__(256) void reduce_sig(const float* __restrict__ part,
                                                  const float* __restrict__ bR,
                                                  float* __restrict__ out, int total4) {
  const int i = blockIdx.x * 256 + threadIdx.x;
  if (i >= total4) return;
  const float4* p = reinterpret_cast<const float4*>(part);
  const float4 a = p[i], b = p[i + total4], c = p[i + 2 * total4], d = p[i + 3 * total4];
  const int col = (i * 4) & 127;
  const float4 bb = *reinterpret_cast<const float4*>(&bR[col]);
  float4 o;
  o.x = 1.f / (1.f + expf(-(a.x + b.x + c.x + d.x + bb.x)));
  o.y = 1.f / (1.f + expf(-(a.y + b.y + c.y + d.y + bb.y)));
  o.z = 1.f / (1.f + expf(-(a.z + b.z + c.z + d.z + bb.z)));
  o.w = 1.f / (1.f + expf(-(a.w + b.w + c.w + d.w + bb.w)));
  reinterpret_cast<float4*>(out)[i] = o;
}

// ---------------- threshold = sigmoid(h @ Wt + bt), one wave per row ----------------
__global__ __launch_bounds__(256) void thresh_kernel(const float* __restrict__ h,
                                                     const float* __restrict__ Wt,
                                                     const float* __restrict__ bt,
                                                     float* __restrict__ out, int B) {
  const int lane = threadIdx.x & 63;
  const int row = blockIdx.x * 4 + (threadIdx.x >> 6);
  if (row >= B) return;
  const float* hr = h + (size_t)row * 1024;
  float s = 0.f;
#pragma unroll
  for (int it = 0; it < 4; ++it) {
    const int k = (lane + it * 64) * 4;
    const float4 a = *reinterpret_cast<const float4*>(&hr[k]);
    const float4 w = *reinterpret_cast<const float4*>(&Wt[k]);
    s += a.x * w.x + a.y * w.y + a.z * w.z + a.w * w.w;
  }
#pragma unroll
  for (int off = 32; off; off >>= 1) s += __shfl_xor(s, off);
  if (lane == 0) out[row] = 1.f / (1.f + expf(-(s + bt[0])));
}

// ---------------- program decode ----------------
__global__ __launch_bounds__(256) void decode_prog(const float* __restrict__ P_op,
                                                   const float* __restrict__ P_dst,
                                                   const float* __restrict__ P_s1,
                                                   const float* __restrict__ P_s2,
                                                   const float* __restrict__ P_imm,
                                                   const float* __restrict__ Plen,
                                                   float* __restrict__ prog,
                                                   float* __restrict__ plen, int BT) {
  const int i = blockIdx.x * 256 + threadIdx.x;
  if (i >= BT) return;
  const float* po = P_op + (size_t)i * 4;
  const float op = po[0] + 2.f * po[1] + 4.f * po[2] + 8.f * po[3];
  const float* pd = P_dst + (size_t)i * 3;
  const float dv = pd[0] + 2.f * pd[1] + 4.f * pd[2];
  const float* p1 = P_s1 + (size_t)i * 3;
  const float s1v = p1[0] + 2.f * p1[1] + 4.f * p1[2];
  const float* p2 = P_s2 + (size_t)i * 3;
  const float s2v = p2[0] + 2.f * p2[1] + 4.f * p2[2];
  const float* pi = P_imm + (size_t)i * 3;
  const float imv = pi[0] + 2.f * pi[1] + 4.f * pi[2];
  float* o = prog + (size_t)i * 5;
  o[0] = op; o[1] = dv; o[2] = s1v; o[3] = s2v; o[4] = imv;
  if ((i & 15) == 0) {
    const int b = i >> 4;
    const float* pl = Plen + (size_t)b * 4;
    plen[b] = pl[0] + 2.f * pl[1] + 4.f * pl[2] + 8.f * pl[3];
  }
}

// ---------------- per-(b,g) soft-VM scan ----------------
__global__ __launch_bounds__(256) void scan_kernel(const float* __restrict__ Rbits,
                                                   const float* __restrict__ prog,
                                                   const float* __restrict__ plen,
                                                   float* __restrict__ Rfinal, int B) {
  __shared__ float s_bits[16][128];
  __shared__ float s_prog[16][80];
  __shared__ float s_plen[16];
  const int tid = threadIdx.x;
  const int b0 = blockIdx.x * 16;
#pragma unroll
  for (int j = 0; j < 8; ++j) {
    const int f = tid + 256 * j;
    s_bits[f >> 7][f & 127] = Rbits[(size_t)(b0 + (f >> 7)) * 128 + (f & 127)];
  }
#pragma unroll
  for (int j = 0; j < 5; ++j) {
    const int f = tid + 256 * j;
    s_prog[f / 80][f % 80] = prog[(size_t)b0 * 80 + f];
  }
  if (tid < 16) s_plen[tid] = plen[b0 + tid];
  __syncthreads();

  const int lb = tid >> 4, g = tid & 15;
  const int bg = (b0 + lb) * 16 + g;

  // partitionable threefry: k2 = full pair of threefry((0,42),(0,1)); bits[n] = fold(threefry(k2,(0,n)))
  uint32_t k2a, k2b;
  { uint32_t x0 = 0u, x1 = 1u; threefry2x32(0u, 42u, x0, x1); k2a = x0; k2b = x1; }
  uint32_t p0, p1;
  {
    uint32_t x0 = 0u, x1 = (uint32_t)bg * 2u;
    threefry2x32(k2a, k2b, x0, x1);
    p0 = (x0 ^ x1) & 127u;
  }
  {
    uint32_t x0 = 0u, x1 = (uint32_t)bg * 2u + 1u;
    threefry2x32(k2a, k2b, x0, x1);
    p1 = (x0 ^ x1) & 127u;
  }

  float R[8], M[8];
#pragma unroll
  for (int r = 0; r < 8; ++r) {
    float a = 0.f;
#pragma unroll
    for (int bit = 0; bit < 16; ++bit) {
      const int pos = r * 16 + bit;
      float v = s_bits[lb][pos];
      const bool flip = (g != 0) && ((int)p0 == pos || (int)p1 == pos);
      v = flip ? 1.0f - v : v;
      a = fmaf(v, (float)(1 << bit), a);
    }
    R[r] = a;
    M[r] = 0.f;
  }

  const float pl = s_plen[lb];
  for (int t = 0; t < 16; ++t) {
    const float op = s_prog[lb][t * 5 + 0];
    const float dst = s_prog[lb][t * 5 + 1];
    const float sa = s_prog[lb][t * 5 + 2];
    const float sb = s_prog[lb][t * 5 + 3];
    const float imm = s_prog[lb][t * 5 + 4];
    const float active = fminf(fmaxf(pl - (float)t, 0.f), 1.f);
    float r1 = 0.f, r2 = 0.f, m1 = 0.f, old = 0.f;
    float wd[8];
#pragma unroll
    for (int i = 0; i < 8; ++i) {
      const float w1 = fmaxf(1.f - fabsf(sa - (float)i), 0.f);
      const float w2 = fmaxf(1.f - fabsf(sb - (float)i), 0.f);
      wd[i] = fmaxf(1.f - fabsf(dst - (float)i), 0.f);
      r1 = fmaf(w1, R[i], r1);
      r2 = fmaf(w2, R[i], r2);
      m1 = fmaf(w1, M[i], m1);
      old = fmaf(wd[i], R[i], old);
    }
    float results[16];
    results[0] = old;               results[1] = r1 + r2;
    results[2] = r1 - r2;           results[3] = r1 * r2 * (1.f / 65536.f);
    results[4] = r1;                results[5] = imm;
    results[6] = r1 + imm;          results[7] = fmaxf(r1, r2);
    results[8] = fminf(r1, r2);     results[9] = -r1;
    results[10] = 0.5f * r1;        results[11] = r2;
    results[12] = m1;               results[13] = old;
    results[14] = fabsf(r1);        results[15] = old;
    float res = 0.f;
    const float pstore = fmaxf(1.f - fabsf(op - 13.f), 0.f);
#pragma unroll
    for (int o = 0; o < 16; ++o) res = fmaf(fmaxf(1.f - fabsf(op - (float)o), 0.f), results[o], res);
#pragma unroll
    for (int i = 0; i < 8; ++i) {
      R[i] = fmaf(active * wd[i], res - R[i], R[i]);
      M[i] = fmaf(active * pstore * wd[i], r1 - M[i], M[i]);
    }
  }

  float* outp = Rfinal + (size_t)bg * 8;
#pragma unroll
  for (int r = 0; r < 8; ++r) outp[r] = R[r];
}

// ---------------- reg_hidden = LN(R @ W_r2h + b) * g + b ; one wave per (b,g) ----------------
__global__ __launch_bounds__(256) void final_expand(const float* __restrict__ Rf,
                                                    const float* __restrict__ W,
                                                    const float* __restrict__ bias,
                                                    const float* __restrict__ gam,
                                                    const float* __restrict__ bet,
                                                    float* __restrict__ out) {
  const int lane = threadIdx.x & 63;
  const int bg = blockIdx.x * 4 + (threadIdx.x >> 6);
  const float* Rp = Rf + (size_t)bg * 8;
  float r[8];
#pragma unroll
  for (int i = 0; i < 8; ++i) r[i] = Rp[i];
  const int h0 = lane * 8;
  float x[8];
#pragma unroll
  for (int j = 0; j < 8; ++j) x[j] = bias[h0 + j];
#pragma unroll
  for (int reg = 0; reg < 8; ++reg) {
    const float4 wa = *reinterpret_cast<const float4*>(&W[reg * 512 + h0]);
    const float4 wb = *reinterpret_cast<const float4*>(&W[reg * 512 + h0 + 4]);
    x[0] = fmaf(r[reg], wa.x, x[0]); x[1] = fmaf(r[reg], wa.y, x[1]);
    x[2] = fmaf(r[reg], wa.z, x[2]); x[3] = fmaf(r[reg], wa.w, x[3]);
    x[4] = fmaf(r[reg], wb.x, x[4]); x[5] = fmaf(r[reg], wb.y, x[5]);
    x[6] = fmaf(r[reg], wb.z, x[6]); x[7] = fmaf(r[reg], wb.w, x[7]);
  }
  float s1 = 0.f, s2 = 0.f;
#pragma unroll
  for (int j = 0; j < 8; ++j) { s1 += x[j]; s2 = fmaf(x[j], x[j], s2); }
#pragma unroll
  for (int off = 32; off; off >>= 1) { s1 += __shfl_xor(s1, off); s2 += __shfl_xor(s2, off); }
  const float mean = s1 * (1.f / 512.f);
  const float var = s2 * (1.f / 512.f) - mean * mean;
  const float inv = rsqrtf(var + 1e-5f);
  float y[8];
#pragma unroll
  for (int j = 0; j < 8; ++j) y[j] = (x[j] - mean) * inv * gam[h0 + j] + bet[h0 + j];
  float* dst = out + (size_t)bg * 512 + h0;
  *reinterpret_cast<float4*>(dst) = make_float4(y[0], y[1], y[2], y[3]);
  *reinterpret_cast<float4*>(dst + 4) = make_float4(y[4], y[5], y[6], y[7]);
}

// ---------------- launch ----------------
extern "C" void kernel_launch(void* const* d_in, const int* in_sizes, int n_in,
                              void* d_out, int out_size, void* d_ws, size_t ws_size,
                              hipStream_t stream) {
  const float* z    = (const float*)d_in[0];
  const float* P_op = (const float*)d_in[1];
  const float* P_dst= (const float*)d_in[2];
  const float* P_s1 = (const float*)d_in[3];
  const float* P_s2 = (const float*)d_in[4];
  const float* P_imm= (const float*)d_in[5];
  const float* Plen = (const float*)d_in[6];
  const float* W1   = (const float*)d_in[8];
  const float* b1   = (const float*)d_in[9];
  const float* WR   = (const float*)d_in[10];
  const float* bR   = (const float*)d_in[11];
  const float* Wt   = (const float*)d_in[12];
  const float* bt   = (const float*)d_in[13];
  const float* W_r2h= (const float*)d_in[14];
  const float* b_r2h= (const float*)d_in[15];
  const float* ln_g = (const float*)d_in[16];
  const float* ln_b = (const float*)d_in[17];

  const int B = in_sizes[0] / 512;  // 8192
  float* out = (float*)d_out;
  float* h       = out;                                // B*1024 f32, overwritten by expand later
  float* part    = out + (size_t)(1 << 25);            // 4 * B*128 f32 partials (K-split), also overwritten
  float* thr_out = out + (size_t)B * 16 * 512;         // threshold output region

  float* ws = (float*)d_ws;
  float* Rbits  = ws;                                  // B*128
  float* prog   = Rbits + (size_t)B * 128;             // B*16*5
  float* plen   = prog + (size_t)B * 80;               // B
  float* Rfinal = plen + B;                            // B*16*8

  const dim3 blk(256);
  // GEMM1: h = relu(z @ W1 + b1)   [8192x512] x [512x1024]
  gemm64<0><<<dim3(1024 / 64, B / 64, 1), blk, 0, stream>>>(z, W1, b1, h, 1024, 512, 512, 0);
  // GEMM2 partials: K=1024 split x4  [8192x1024] x [1024x128]
  gemm64<2><<<dim3(128 / 64, B / 64, 4), blk, 0, stream>>>(h, WR, nullptr, part, 128, 1024, 256,
                                                           (size_t)B * 128);
  reduce_sig<<<dim3((B * 128 / 4 + 255) / 256), blk, 0, stream>>>(part, bR, Rbits, B * 128 / 4);
  thresh_kernel<<<dim3(B / 4), blk, 0, stream>>>(h, Wt, bt, thr_out, B);
  decode_prog<<<dim3((B * 16 + 255) / 256), blk, 0, stream>>>(P_op, P_dst, P_s1, P_s2, P_imm,
                                                              Plen, prog, plen, B * 16);
  scan_kernel<<<dim3(B / 16), blk, 0, stream>>>(Rbits, prog, plen, Rfinal, B);
  final_expand<<<dim3(B * 16 / 4), blk, 0, stream>>>(Rfinal, W_r2h, b_r2h, ln_g, ln_b, out);
}

// Round 4
// 197.740 us; speedup vs baseline: 1.5797x; 1.4867x over previous
//
#include <hip/hip_runtime.h>
#include <stdint.h>

typedef __attribute__((ext_vector_type(8))) short short8;
typedef __attribute__((ext_vector_type(4))) float f32x4;
typedef __attribute__((ext_vector_type(8))) unsigned short ushort8;
typedef __attribute__((ext_vector_type(4))) unsigned short ushort4v;

__device__ __forceinline__ unsigned short f2bf(float f) {
  uint32_t u = __float_as_uint(f);
  uint32_t r = (u + 0x7fffu + ((u >> 16) & 1u)) >> 16;  // RNE
  return (unsigned short)r;
}

// ---------------- Threefry-2x32-20 (exact JAX partitionable semantics) ----------------
__device__ __forceinline__ uint32_t rotl32(uint32_t v, int d) { return (v << d) | (v >> (32 - d)); }

__device__ __forceinline__ void threefry2x32(uint32_t k0, uint32_t k1, uint32_t& x0, uint32_t& x1) {
  const uint32_t ks2 = k0 ^ k1 ^ 0x1BD11BDAu;
  x0 += k0; x1 += k1;
  x0 += x1; x1 = rotl32(x1, 13); x1 ^= x0;
  x0 += x1; x1 = rotl32(x1, 15); x1 ^= x0;
  x0 += x1; x1 = rotl32(x1, 26); x1 ^= x0;
  x0 += x1; x1 = rotl32(x1, 6);  x1 ^= x0;
  x0 += k1; x1 += ks2 + 1u;
  x0 += x1; x1 = rotl32(x1, 17); x1 ^= x0;
  x0 += x1; x1 = rotl32(x1, 29); x1 ^= x0;
  x0 += x1; x1 = rotl32(x1, 16); x1 ^= x0;
  x0 += x1; x1 = rotl32(x1, 24); x1 ^= x0;
  x0 += ks2; x1 += k0 + 2u;
  x0 += x1; x1 = rotl32(x1, 13); x1 ^= x0;
  x0 += x1; x1 = rotl32(x1, 15); x1 ^= x0;
  x0 += x1; x1 = rotl32(x1, 26); x1 ^= x0;
  x0 += x1; x1 = rotl32(x1, 6);  x1 ^= x0;
  x0 += k0; x1 += k1 + 3u;
  x0 += x1; x1 = rotl32(x1, 17); x1 ^= x0;
  x0 += x1; x1 = rotl32(x1, 29); x1 ^= x0;
  x0 += x1; x1 = rotl32(x1, 16); x1 ^= x0;
  x0 += x1; x1 = rotl32(x1, 24); x1 ^= x0;
  x0 += k1; x1 += ks2 + 4u;
  x0 += x1; x1 = rotl32(x1, 13); x1 ^= x0;
  x0 += x1; x1 = rotl32(x1, 15); x1 ^= x0;
  x0 += x1; x1 = rotl32(x1, 26); x1 ^= x0;
  x0 += x1; x1 = rotl32(x1, 6);  x1 ^= x0;
  x0 += ks2; x1 += k0 + 5u;
}

// ---------------- transpose + cast: W1 (512x1024) -> W1t (1024x512) bf16; WR (1024x128) -> WRt ----------------
__global__ __launch_bounds__(256) void transpose_cast(const float* __restrict__ W1,
                                                      const float* __restrict__ WR,
                                                      unsigned short* __restrict__ W1t,
                                                      unsigned short* __restrict__ WRt) {
  __shared__ float t[32][33];
  const int tid = threadIdx.x;
  const float* src; unsigned short* dst; int N, K, k0, n0;
  if (blockIdx.x < 512) {            // W1: K=512 rows, N=1024 cols -> 16 x 32 tiles
    src = W1; dst = W1t; N = 1024; K = 512;
    k0 = (blockIdx.x & 15) * 32; n0 = (blockIdx.x >> 4) * 32;
  } else {                            // WR: K=1024 rows, N=128 cols -> 32 x 4 tiles
    const int b2 = blockIdx.x - 512;
    src = WR; dst = WRt; N = 128; K = 1024;
    k0 = (b2 & 31) * 32; n0 = (b2 >> 5) * 32;
  }
  {
    const int row = tid >> 3, c4 = (tid & 7) * 4;
    const float4 v = *reinterpret_cast<const float4*>(&src[(size_t)(k0 + row) * N + n0 + c4]);
    t[row][c4] = v.x; t[row][c4 + 1] = v.y; t[row][c4 + 2] = v.z; t[row][c4 + 3] = v.w;
  }
  __syncthreads();
  {
    const int n = tid >> 3, k4 = (tid & 7) * 4;
    ushort4v o;
    o.x = f2bf(t[k4 + 0][n]); o.y = f2bf(t[k4 + 1][n]);
    o.z = f2bf(t[k4 + 2][n]); o.w = f2bf(t[k4 + 3][n]);
    *reinterpret_cast<ushort4v*>(&dst[(size_t)(n0 + n) * K + k0 + k4]) = o;
  }
}

// ---------------- bf16 MFMA GEMM: C = A(f32,MxK) x Bt(bf16,NxK)^T ; 128x128 tile, BK=32 ----------------
// EPI 0: relu(x+bias) -> f32   EPI 2: raw f32 partial (blockIdx.z = K-slice)
template <int EPI>
__global__ __launch_bounds__(256) void gemm_mfma(const float* __restrict__ A,
                                                 const unsigned short* __restrict__ Bt,
                                                 const float* __restrict__ bias,
                                                 float* __restrict__ C,
                                                 int N, int K, int kSplit, size_t zStride) {
  __shared__ unsigned short As[128][56];  // 112B row stride = 7x16B -> conflict-free b128
  __shared__ unsigned short Bs[128][56];
  const int tid = threadIdx.x;
  const int lane = tid & 63, wave = tid >> 6;
  const int wm = wave >> 1, wn = wave & 1;
  const int bm = blockIdx.y * 128, bn = blockIdx.x * 128;
  const int k_lo = blockIdx.z * kSplit, k_hi = k_lo + kSplit;

  f32x4 acc[4][4];
#pragma unroll
  for (int i = 0; i < 4; ++i)
#pragma unroll
    for (int j = 0; j < 4; ++j) acc[i][j] = (f32x4)0.f;

  const int sm = tid >> 1, skh = (tid & 1) * 16;   // staging row + k-half

  for (int k0 = k_lo; k0 < k_hi; k0 += 32) {
    // stage A (f32 -> bf16): 128 rows x 32 k
    {
      const float* ap = &A[(size_t)(bm + sm) * K + k0 + skh];
      const float4 f0 = *reinterpret_cast<const float4*>(ap);
      const float4 f1 = *reinterpret_cast<const float4*>(ap + 4);
      const float4 f2 = *reinterpret_cast<const float4*>(ap + 8);
      const float4 f3 = *reinterpret_cast<const float4*>(ap + 12);
      ushort8 u0, u1;
      u0[0] = f2bf(f0.x); u0[1] = f2bf(f0.y); u0[2] = f2bf(f0.z); u0[3] = f2bf(f0.w);
      u0[4] = f2bf(f1.x); u0[5] = f2bf(f1.y); u0[6] = f2bf(f1.z); u0[7] = f2bf(f1.w);
      u1[0] = f2bf(f2.x); u1[1] = f2bf(f2.y); u1[2] = f2bf(f2.z); u1[3] = f2bf(f2.w);
      u1[4] = f2bf(f3.x); u1[5] = f2bf(f3.y); u1[6] = f2bf(f3.z); u1[7] = f2bf(f3.w);
      *reinterpret_cast<ushort8*>(&As[sm][skh]) = u0;
      *reinterpret_cast<ushort8*>(&As[sm][skh + 8]) = u1;
    }
    // stage B (already bf16, NxK row-major): 128 n-rows x 32 k
    {
      const unsigned short* bp = &Bt[(size_t)(bn + sm) * K + k0 + skh];
      const ushort8 b0 = *reinterpret_cast<const ushort8*>(bp);
      const ushort8 b1 = *reinterpret_cast<const ushort8*>(bp + 8);
      *reinterpret_cast<ushort8*>(&Bs[sm][skh]) = b0;
      *reinterpret_cast<ushort8*>(&Bs[sm][skh + 8]) = b1;
    }
    __syncthreads();

    const int fr = lane & 15, kc = (lane >> 4) * 8;
    short8 af[4], bfr[4];
#pragma unroll
    for (int f = 0; f < 4; ++f)
      af[f] = *reinterpret_cast<const short8*>(&As[wm * 64 + f * 16 + fr][kc]);
#pragma unroll
    for (int f = 0; f < 4; ++f)
      bfr[f] = *reinterpret_cast<const short8*>(&Bs[wn * 64 + f * 16 + fr][kc]);
#pragma unroll
    for (int fm = 0; fm < 4; ++fm)
#pragma unroll
      for (int fn = 0; fn < 4; ++fn)
        acc[fm][fn] = __builtin_amdgcn_mfma_f32_16x16x32_bf16(af[fm], bfr[fn], acc[fm][fn], 0, 0, 0);
    __syncthreads();
  }

  // epilogue: D col = lane&15, row = (lane>>4)*4 + r
  float* Cp = C + (size_t)blockIdx.z * zStride;
  const int lr = (lane >> 4) * 4, lc = lane & 15;
#pragma unroll
  for (int fn = 0; fn < 4; ++fn) {
    const int col = bn + wn * 64 + fn * 16 + lc;
    const float bv = (EPI == 0) ? bias[col] : 0.f;
#pragma unroll
    for (int fm = 0; fm < 4; ++fm) {
      const int row0 = bm + wm * 64 + fm * 16 + lr;
#pragma unroll
      for (int r = 0; r < 4; ++r) {
        float v = acc[fm][fn][r];
        if (EPI == 0) v = fmaxf(v + bv, 0.f);
        Cp[(size_t)(row0 + r) * N + col] = v;
      }
    }
  }
}

// ---------------- sum 8 K-split partials + bias -> sigmoid -> Rbits ----------------
__global__ __launch_bounds__(256) void reduce_sig(const float* __restrict__ part,
                                                  const float* __restrict__ bR,
                                                  float* __restrict__ out, int total4) {
  const int i = blockIdx.x * 256 + threadIdx.x;
  if (i >= total4) return;
  const float4* p = reinterpret_cast<const float4*>(part);
  float4 s = p[i];
#pragma unroll
  for (int j = 1; j < 8; ++j) {
    const float4 q = p[i + (size_t)j * total4];
    s.x += q.x; s.y += q.y; s.z += q.z; s.w += q.w;
  }
  const int col = (i * 4) & 127;
  const float4 bb = *reinterpret_cast<const float4*>(&bR[col]);
  float4 o;
  o.x = 1.f / (1.f + expf(-(s.x + bb.x)));
  o.y = 1.f / (1.f + expf(-(s.y + bb.y)));
  o.z = 1.f / (1.f + expf(-(s.z + bb.z)));
  o.w = 1.f / (1.f + expf(-(s.w + bb.w)));
  reinterpret_cast<float4*>(out)[i] = o;
}

// ---------------- threshold = sigmoid(h @ Wt + bt), one wave per row ----------------
__global__ __launch_bounds__(256) void thresh_kernel(const float* __restrict__ h,
                                                     const float* __restrict__ Wt,
                                                     const float* __restrict__ bt,
                                                     float* __restrict__ out, int B) {
  const int lane = threadIdx.x & 63;
  const int row = blockIdx.x * 4 + (threadIdx.x >> 6);
  if (row >= B) return;
  const float* hr = h + (size_t)row * 1024;
  float s = 0.f;
#pragma unroll
  for (int it = 0; it < 4; ++it) {
    const int k = (lane + it * 64) * 4;
    const float4 a = *reinterpret_cast<const float4*>(&hr[k]);
    const float4 w = *reinterpret_cast<const float4*>(&Wt[k]);
    s += a.x * w.x + a.y * w.y + a.z * w.z + a.w * w.w;
  }
#pragma unroll
  for (int off = 32; off; off >>= 1) s += __shfl_xor(s, off);
  if (lane == 0) out[row] = 1.f / (1.f + expf(-(s + bt[0])));
}

// ---------------- program decode ----------------
__global__ __launch_bounds__(256) void decode_prog(const float* __restrict__ P_op,
                                                   const float* __restrict__ P_dst,
                                                   const float* __restrict__ P_s1,
                                                   const float* __restrict__ P_s2,
                                                   const float* __restrict__ P_imm,
                                                   const float* __restrict__ Plen,
                                                   float* __restrict__ prog,
                                                   float* __restrict__ plen, int BT) {
  const int i = blockIdx.x * 256 + threadIdx.x;
  if (i >= BT) return;
  const float* po = P_op + (size_t)i * 4;
  const float op = po[0] + 2.f * po[1] + 4.f * po[2] + 8.f * po[3];
  const float* pd = P_dst + (size_t)i * 3;
  const float dv = pd[0] + 2.f * pd[1] + 4.f * pd[2];
  const float* p1 = P_s1 + (size_t)i * 3;
  const float s1v = p1[0] + 2.f * p1[1] + 4.f * p1[2];
  const float* p2 = P_s2 + (size_t)i * 3;
  const float s2v = p2[0] + 2.f * p2[1] + 4.f * p2[2];
  const float* pi = P_imm + (size_t)i * 3;
  const float imv = pi[0] + 2.f * pi[1] + 4.f * pi[2];
  float* o = prog + (size_t)i * 5;
  o[0] = op; o[1] = dv; o[2] = s1v; o[3] = s2v; o[4] = imv;
  if ((i & 15) == 0) {
    const int b = i >> 4;
    const float* pl = Plen + (size_t)b * 4;
    plen[b] = pl[0] + 2.f * pl[1] + 4.f * pl[2] + 8.f * pl[3];
  }
}

// ---------------- per-(b,g) soft-VM scan ----------------
__global__ __launch_bounds__(256) void scan_kernel(const float* __restrict__ Rbits,
                                                   const float* __restrict__ prog,
                                                   const float* __restrict__ plen,
                                                   float* __restrict__ Rfinal, int B) {
  __shared__ float s_bits[16][128];
  __shared__ float s_prog[16][80];
  __shared__ float s_plen[16];
  const int tid = threadIdx.x;
  const int b0 = blockIdx.x * 16;
#pragma unroll
  for (int j = 0; j < 8; ++j) {
    const int f = tid + 256 * j;
    s_bits[f >> 7][f & 127] = Rbits[(size_t)(b0 + (f >> 7)) * 128 + (f & 127)];
  }
#pragma unroll
  for (int j = 0; j < 5; ++j) {
    const int f = tid + 256 * j;
    s_prog[f / 80][f % 80] = prog[(size_t)b0 * 80 + f];
  }
  if (tid < 16) s_plen[tid] = plen[b0 + tid];
  __syncthreads();

  const int lb = tid >> 4, g = tid & 15;
  const int bg = (b0 + lb) * 16 + g;

  uint32_t k2a, k2b;
  { uint32_t x0 = 0u, x1 = 1u; threefry2x32(0u, 42u, x0, x1); k2a = x0; k2b = x1; }
  uint32_t p0, p1;
  {
    uint32_t x0 = 0u, x1 = (uint32_t)bg * 2u;
    threefry2x32(k2a, k2b, x0, x1);
    p0 = (x0 ^ x1) & 127u;
  }
  {
    uint32_t x0 = 0u, x1 = (uint32_t)bg * 2u + 1u;
    threefry2x32(k2a, k2b, x0, x1);
    p1 = (x0 ^ x1) & 127u;
  }

  float R[8], M[8];
#pragma unroll
  for (int r = 0; r < 8; ++r) {
    float a = 0.f;
#pragma unroll
    for (int bit = 0; bit < 16; ++bit) {
      const int pos = r * 16 + bit;
      float v = s_bits[lb][pos];
      const bool flip = (g != 0) && ((int)p0 == pos || (int)p1 == pos);
      v = flip ? 1.0f - v : v;
      a = fmaf(v, (float)(1 << bit), a);
    }
    R[r] = a;
    M[r] = 0.f;
  }

  const float pl = s_plen[lb];
  for (int t = 0; t < 16; ++t) {
    const float op = s_prog[lb][t * 5 + 0];
    const float dst = s_prog[lb][t * 5 + 1];
    const float sa = s_prog[lb][t * 5 + 2];
    const float sb = s_prog[lb][t * 5 + 3];
    const float imm = s_prog[lb][t * 5 + 4];
    const float active = fminf(fmaxf(pl - (float)t, 0.f), 1.f);
    float r1 = 0.f, r2 = 0.f, m1 = 0.f, old = 0.f;
    float wd[8];
#pragma unroll
    for (int i = 0; i < 8; ++i) {
      const float w1 = fmaxf(1.f - fabsf(sa - (float)i), 0.f);
      const float w2 = fmaxf(1.f - fabsf(sb - (float)i), 0.f);
      wd[i] = fmaxf(1.f - fabsf(dst - (float)i), 0.f);
      r1 = fmaf(w1, R[i], r1);
      r2 = fmaf(w2, R[i], r2);
      m1 = fmaf(w1, M[i], m1);
      old = fmaf(wd[i], R[i], old);
    }
    float results[16];
    results[0] = old;               results[1] = r1 + r2;
    results[2] = r1 - r2;           results[3] = r1 * r2 * (1.f / 65536.f);
    results[4] = r1;                results[5] = imm;
    results[6] = r1 + imm;          results[7] = fmaxf(r1, r2);
    results[8] = fminf(r1, r2);     results[9] = -r1;
    results[10] = 0.5f * r1;        results[11] = r2;
    results[12] = m1;               results[13] = old;
    results[14] = fabsf(r1);        results[15] = old;
    float res = 0.f;
    const float pstore = fmaxf(1.f - fabsf(op - 13.f), 0.f);
#pragma unroll
    for (int o = 0; o < 16; ++o) res = fmaf(fmaxf(1.f - fabsf(op - (float)o), 0.f), results[o], res);
#pragma unroll
    for (int i = 0; i < 8; ++i) {
      R[i] = fmaf(active * wd[i], res - R[i], R[i]);
      M[i] = fmaf(active * pstore * wd[i], r1 - M[i], M[i]);
    }
  }

  float* outp = Rfinal + (size_t)bg * 8;
#pragma unroll
  for (int r = 0; r < 8; ++r) outp[r] = R[r];
}

// ---------------- reg_hidden = LN(R @ W_r2h + b) * g + b ; one wave per (b,g) ----------------
__global__ __launch_bounds__(256) void final_expand(const float* __restrict__ Rf,
                                                    const float* __restrict__ W,
                                                    const float* __restrict__ bias,
                                                    const float* __restrict__ gam,
                                                    const float* __restrict__ bet,
                                                    float* __restrict__ out) {
  const int lane = threadIdx.x & 63;
  const int bg = blockIdx.x * 4 + (threadIdx.x >> 6);
  const float* Rp = Rf + (size_t)bg * 8;
  float r[8];
#pragma unroll
  for (int i = 0; i < 8; ++i) r[i] = Rp[i];
  const int h0 = lane * 8;
  float x[8];
#pragma unroll
  for (int j = 0; j < 8; ++j) x[j] = bias[h0 + j];
#pragma unroll
  for (int reg = 0; reg < 8; ++reg) {
    const float4 wa = *reinterpret_cast<const float4*>(&W[reg * 512 + h0]);
    const float4 wb = *reinterpret_cast<const float4*>(&W[reg * 512 + h0 + 4]);
    x[0] = fmaf(r[reg], wa.x, x[0]); x[1] = fmaf(r[reg], wa.y, x[1]);
    x[2] = fmaf(r[reg], wa.z, x[2]); x[3] = fmaf(r[reg], wa.w, x[3]);
    x[4] = fmaf(r[reg], wb.x, x[4]); x[5] = fmaf(r[reg], wb.y, x[5]);
    x[6] = fmaf(r[reg], wb.z, x[6]); x[7] = fmaf(r[reg], wb.w, x[7]);
  }
  float s1 = 0.f, s2 = 0.f;
#pragma unroll
  for (int j = 0; j < 8; ++j) { s1 += x[j]; s2 = fmaf(x[j], x[j], s2); }
#pragma unroll
  for (int off = 32; off; off >>= 1) { s1 += __shfl_xor(s1, off); s2 += __shfl_xor(s2, off); }
  const float mean = s1 * (1.f / 512.f);
  const float var = s2 * (1.f / 512.f) - mean * mean;
  const float inv = rsqrtf(var + 1e-5f);
  float y[8];
#pragma unroll
  for (int j = 0; j < 8; ++j) y[j] = (x[j] - mean) * inv * gam[h0 + j] + bet[h0 + j];
  float* dst = out + (size_t)bg * 512 + h0;
  *reinterpret_cast<float4*>(dst) = make_float4(y[0], y[1], y[2], y[3]);
  *reinterpret_cast<float4*>(dst + 4) = make_float4(y[4], y[5], y[6], y[7]);
}

// ---------------- launch ----------------
extern "C" void kernel_launch(void* const* d_in, const int* in_sizes, int n_in,
                              void* d_out, int out_size, void* d_ws, size_t ws_size,
                              hipStream_t stream) {
  const float* z    = (const float*)d_in[0];
  const float* P_op = (const float*)d_in[1];
  const float* P_dst= (const float*)d_in[2];
  const float* P_s1 = (const float*)d_in[3];
  const float* P_s2 = (const float*)d_in[4];
  const float* P_imm= (const float*)d_in[5];
  const float* Plen = (const float*)d_in[6];
  const float* W1   = (const float*)d_in[8];
  const float* b1   = (const float*)d_in[9];
  const float* WR   = (const float*)d_in[10];
  const float* bR   = (const float*)d_in[11];
  const float* Wt   = (const float*)d_in[12];
  const float* bt   = (const float*)d_in[13];
  const float* W_r2h= (const float*)d_in[14];
  const float* b_r2h= (const float*)d_in[15];
  const float* ln_g = (const float*)d_in[16];
  const float* ln_b = (const float*)d_in[17];

  const int B = in_sizes[0] / 512;  // 8192
  float* out = (float*)d_out;
  float* h       = out;                                // B*1024 f32, overwritten by final_expand later
  float* part    = out + (size_t)(1 << 25);            // 8 * B*128 f32 K-split partials, overwritten later
  float* thr_out = out + (size_t)B * 16 * 512;         // threshold output region

  float* ws = (float*)d_ws;
  float* Rbits  = ws;                                  // B*128
  float* prog   = Rbits + (size_t)B * 128;             // B*16*5
  float* plen   = prog + (size_t)B * 80;               // B
  float* Rfinal = plen + B;                            // B*16*8
  unsigned short* W1t = (unsigned short*)(Rfinal + (size_t)B * 128);  // 1024x512 bf16
  unsigned short* WRt = W1t + (size_t)1024 * 512;                     // 128x1024 bf16

  const dim3 blk(256);
  transpose_cast<<<dim3(640), blk, 0, stream>>>(W1, WR, W1t, WRt);
  // GEMM1: h = relu(z @ W1 + b1)   [8192x512] x [512x1024], MFMA bf16
  gemm_mfma<0><<<dim3(1024 / 128, B / 128, 1), blk, 0, stream>>>(z, W1t, b1, h, 1024, 512, 512, 0);
  // GEMM2 partials: [8192x1024] x [1024x128], K split x8
  gemm_mfma<2><<<dim3(1, B / 128, 8), blk, 0, stream>>>(h, WRt, nullptr, part, 128, 1024, 128,
                                                        (size_t)B * 128);
  reduce_sig<<<dim3((B * 128 / 4 + 255) / 256), blk, 0, stream>>>(part, bR, Rbits, B * 128 / 4);
  thresh_kernel<<<dim3(B / 4), blk, 0, stream>>>(h, Wt, bt, thr_out, B);
  decode_prog<<<dim3((B * 16 + 255) / 256), blk, 0, stream>>>(P_op, P_dst, P_s1, P_s2, P_imm,
                                                              Plen, prog, plen, B * 16);
  scan_kernel<<<dim3(B / 16), blk, 0, stream>>>(Rbits, prog, plen, Rfinal, B);
  final_expand<<<dim3(B * 16 / 4), blk, 0, stream>>>(Rfinal, W_r2h, b_r2h, ln_g, ln_b, out);
}

// Round 5
// 192.641 us; speedup vs baseline: 1.6215x; 1.0265x over previous
//
#include <hip/hip_runtime.h>
#include <stdint.h>

typedef __attribute__((ext_vector_type(8))) short short8;
typedef __attribute__((ext_vector_type(4))) float f32x4;
typedef __attribute__((ext_vector_type(8))) unsigned short ushort8;
typedef __attribute__((ext_vector_type(4))) unsigned short ushort4v;

__device__ __forceinline__ unsigned short f2bf(float f) {
  uint32_t u = __float_as_uint(f);
  uint32_t r = (u + 0x7fffu + ((u >> 16) & 1u)) >> 16;  // RNE
  return (unsigned short)r;
}
__device__ __forceinline__ float bf2f(unsigned short v) {
  return __uint_as_float(((uint32_t)v) << 16);
}

// ---------------- Threefry-2x32-20 (exact JAX partitionable semantics) ----------------
__device__ __forceinline__ uint32_t rotl32(uint32_t v, int d) { return (v << d) | (v >> (32 - d)); }

__device__ __forceinline__ void threefry2x32(uint32_t k0, uint32_t k1, uint32_t& x0, uint32_t& x1) {
  const uint32_t ks2 = k0 ^ k1 ^ 0x1BD11BDAu;
  x0 += k0; x1 += k1;
  x0 += x1; x1 = rotl32(x1, 13); x1 ^= x0;
  x0 += x1; x1 = rotl32(x1, 15); x1 ^= x0;
  x0 += x1; x1 = rotl32(x1, 26); x1 ^= x0;
  x0 += x1; x1 = rotl32(x1, 6);  x1 ^= x0;
  x0 += k1; x1 += ks2 + 1u;
  x0 += x1; x1 = rotl32(x1, 17); x1 ^= x0;
  x0 += x1; x1 = rotl32(x1, 29); x1 ^= x0;
  x0 += x1; x1 = rotl32(x1, 16); x1 ^= x0;
  x0 += x1; x1 = rotl32(x1, 24); x1 ^= x0;
  x0 += ks2; x1 += k0 + 2u;
  x0 += x1; x1 = rotl32(x1, 13); x1 ^= x0;
  x0 += x1; x1 = rotl32(x1, 15); x1 ^= x0;
  x0 += x1; x1 = rotl32(x1, 26); x1 ^= x0;
  x0 += x1; x1 = rotl32(x1, 6);  x1 ^= x0;
  x0 += k0; x1 += k1 + 3u;
  x0 += x1; x1 = rotl32(x1, 17); x1 ^= x0;
  x0 += x1; x1 = rotl32(x1, 29); x1 ^= x0;
  x0 += x1; x1 = rotl32(x1, 16); x1 ^= x0;
  x0 += x1; x1 = rotl32(x1, 24); x1 ^= x0;
  x0 += k1; x1 += ks2 + 4u;
  x0 += x1; x1 = rotl32(x1, 13); x1 ^= x0;
  x0 += x1; x1 = rotl32(x1, 15); x1 ^= x0;
  x0 += x1; x1 = rotl32(x1, 26); x1 ^= x0;
  x0 += x1; x1 = rotl32(x1, 6);  x1 ^= x0;
  x0 += ks2; x1 += k0 + 5u;
}

// ---------------- z (f32) -> bf16, 8 elements/thread ----------------
__global__ __launch_bounds__(256) void cast_bf16(const float* __restrict__ in,
                                                 unsigned short* __restrict__ o, int n8) {
  const int i = blockIdx.x * 256 + threadIdx.x;
  if (i >= n8) return;
  const float4 a = reinterpret_cast<const float4*>(in)[i * 2];
  const float4 b = reinterpret_cast<const float4*>(in)[i * 2 + 1];
  ushort8 u;
  u[0] = f2bf(a.x); u[1] = f2bf(a.y); u[2] = f2bf(a.z); u[3] = f2bf(a.w);
  u[4] = f2bf(b.x); u[5] = f2bf(b.y); u[6] = f2bf(b.z); u[7] = f2bf(b.w);
  reinterpret_cast<ushort8*>(o)[i] = u;
}

// ---------------- transpose + cast: W1 (512x1024) -> W1t (1024x512) bf16; WR -> WRt ----------------
__global__ __launch_bounds__(256) void transpose_cast(const float* __restrict__ W1,
                                                      const float* __restrict__ WR,
                                                      unsigned short* __restrict__ W1t,
                                                      unsigned short* __restrict__ WRt) {
  __shared__ float t[32][33];
  const int tid = threadIdx.x;
  const float* src; unsigned short* dst; int N, K, k0, n0;
  if (blockIdx.x < 512) {
    src = W1; dst = W1t; N = 1024; K = 512;
    k0 = (blockIdx.x & 15) * 32; n0 = (blockIdx.x >> 4) * 32;
  } else {
    const int b2 = blockIdx.x - 512;
    src = WR; dst = WRt; N = 128; K = 1024;
    k0 = (b2 & 31) * 32; n0 = (b2 >> 5) * 32;
  }
  {
    const int row = tid >> 3, c4 = (tid & 7) * 4;
    const float4 v = *reinterpret_cast<const float4*>(&src[(size_t)(k0 + row) * N + n0 + c4]);
    t[row][c4] = v.x; t[row][c4 + 1] = v.y; t[row][c4 + 2] = v.z; t[row][c4 + 3] = v.w;
  }
  __syncthreads();
  {
    const int n = tid >> 3, k4 = (tid & 7) * 4;
    ushort4v o;
    o.x = f2bf(t[k4 + 0][n]); o.y = f2bf(t[k4 + 1][n]);
    o.z = f2bf(t[k4 + 2][n]); o.w = f2bf(t[k4 + 3][n]);
    *reinterpret_cast<ushort4v*>(&dst[(size_t)(n0 + n) * K + k0 + k4]) = o;
  }
}

// ---------------- bf16 MFMA GEMM: A(bf16,MxK) x Bt(bf16,NxK)^T ; 128x128 tile, BK=32 ----------------
// EPI 0: relu(x+bias) -> bf16   EPI 2: raw f32 partial (blockIdx.z = K-slice)
template <int EPI>
__global__ __launch_bounds__(256) void gemm_bf16(const unsigned short* __restrict__ A,
                                                 const unsigned short* __restrict__ Bt,
                                                 const float* __restrict__ bias,
                                                 void* __restrict__ Cv,
                                                 int N, int K, int kSplit, size_t zStride) {
  __shared__ unsigned short As[128][56];  // 112B row stride -> 2-way (free) ds_read_b128
  __shared__ unsigned short Bs[128][56];
  const int tid = threadIdx.x;
  const int lane = tid & 63, wave = tid >> 6;
  const int wm = wave >> 1, wn = wave & 1;
  const int bm = blockIdx.y * 128, bn = blockIdx.x * 128;
  const int k_lo = blockIdx.z * kSplit, k_hi = k_lo + kSplit;

  f32x4 acc[4][4];
#pragma unroll
  for (int i = 0; i < 4; ++i)
#pragma unroll
    for (int j = 0; j < 4; ++j) acc[i][j] = (f32x4)0.f;

  const int sm = tid >> 1, skh = (tid & 1) * 16;

  for (int k0 = k_lo; k0 < k_hi; k0 += 32) {
    {
      const unsigned short* ap = &A[(size_t)(bm + sm) * K + k0 + skh];
      const ushort8 a0 = *reinterpret_cast<const ushort8*>(ap);
      const ushort8 a1 = *reinterpret_cast<const ushort8*>(ap + 8);
      *reinterpret_cast<ushort8*>(&As[sm][skh]) = a0;
      *reinterpret_cast<ushort8*>(&As[sm][skh + 8]) = a1;
    }
    {
      const unsigned short* bp = &Bt[(size_t)(bn + sm) * K + k0 + skh];
      const ushort8 b0 = *reinterpret_cast<const ushort8*>(bp);
      const ushort8 b1 = *reinterpret_cast<const ushort8*>(bp + 8);
      *reinterpret_cast<ushort8*>(&Bs[sm][skh]) = b0;
      *reinterpret_cast<ushort8*>(&Bs[sm][skh + 8]) = b1;
    }
    __syncthreads();

    const int fr = lane & 15, kc = (lane >> 4) * 8;
    short8 af[4], bfr[4];
#pragma unroll
    for (int f = 0; f < 4; ++f)
      af[f] = *reinterpret_cast<const short8*>(&As[wm * 64 + f * 16 + fr][kc]);
#pragma unroll
    for (int f = 0; f < 4; ++f)
      bfr[f] = *reinterpret_cast<const short8*>(&Bs[wn * 64 + f * 16 + fr][kc]);
#pragma unroll
    for (int fm = 0; fm < 4; ++fm)
#pragma unroll
      for (int fn = 0; fn < 4; ++fn)
        acc[fm][fn] = __builtin_amdgcn_mfma_f32_16x16x32_bf16(af[fm], bfr[fn], acc[fm][fn], 0, 0, 0);
    __syncthreads();
  }

  const int lr = (lane >> 4) * 4, lc = lane & 15;
  if (EPI == 0) {
    unsigned short* Cp = (unsigned short*)Cv;
#pragma unroll
    for (int fn = 0; fn < 4; ++fn) {
      const int col = bn + wn * 64 + fn * 16 + lc;
      const float bv = bias[col];
#pragma unroll
      for (int fm = 0; fm < 4; ++fm) {
        const int row0 = bm + wm * 64 + fm * 16 + lr;
#pragma unroll
        for (int r = 0; r < 4; ++r)
          Cp[(size_t)(row0 + r) * N + col] = f2bf(fmaxf(acc[fm][fn][r] + bv, 0.f));
      }
    }
  } else {
    float* Cp = (float*)Cv + (size_t)blockIdx.z * zStride;
#pragma unroll
    for (int fn = 0; fn < 4; ++fn) {
      const int col = bn + wn * 64 + fn * 16 + lc;
#pragma unroll
      for (int fm = 0; fm < 4; ++fm) {
        const int row0 = bm + wm * 64 + fm * 16 + lr;
#pragma unroll
        for (int r = 0; r < 4; ++r)
          Cp[(size_t)(row0 + r) * N + col] = acc[fm][fn][r];
      }
    }
  }
}

// ---------------- sum 8 K-split partials + bias -> sigmoid -> Rbits ----------------
__global__ __launch_bounds__(256) void reduce_sig(const float* __restrict__ part,
                                                  const float* __restrict__ bR,
                                                  float* __restrict__ out, int total4) {
  const int i = blockIdx.x * 256 + threadIdx.x;
  if (i >= total4) return;
  const float4* p = reinterpret_cast<const float4*>(part);
  float4 s = p[i];
#pragma unroll
  for (int j = 1; j < 8; ++j) {
    const float4 q = p[i + (size_t)j * total4];
    s.x += q.x; s.y += q.y; s.z += q.z; s.w += q.w;
  }
  const int col = (i * 4) & 127;
  const float4 bb = *reinterpret_cast<const float4*>(&bR[col]);
  float4 o;
  o.x = 1.f / (1.f + expf(-(s.x + bb.x)));
  o.y = 1.f / (1.f + expf(-(s.y + bb.y)));
  o.z = 1.f / (1.f + expf(-(s.z + bb.z)));
  o.w = 1.f / (1.f + expf(-(s.w + bb.w)));
  reinterpret_cast<float4*>(out)[i] = o;
}

// ---------------- threshold = sigmoid(h @ Wt + bt), h in bf16, one wave per row ----------------
__global__ __launch_bounds__(256) void thresh_kernel(const unsigned short* __restrict__ h,
                                                     const float* __restrict__ Wt,
                                                     const float* __restrict__ bt,
                                                     float* __restrict__ out, int B) {
  const int lane = threadIdx.x & 63;
  const int row = blockIdx.x * 4 + (threadIdx.x >> 6);
  if (row >= B) return;
  const unsigned short* hr = h + (size_t)row * 1024;
  float s = 0.f;
#pragma unroll
  for (int it = 0; it < 2; ++it) {
    const int k = (lane + it * 64) * 8;
    const ushort8 a = *reinterpret_cast<const ushort8*>(&hr[k]);
    const float4 w0 = *reinterpret_cast<const float4*>(&Wt[k]);
    const float4 w1 = *reinterpret_cast<const float4*>(&Wt[k + 4]);
    s += bf2f(a[0]) * w0.x + bf2f(a[1]) * w0.y + bf2f(a[2]) * w0.z + bf2f(a[3]) * w0.w;
    s += bf2f(a[4]) * w1.x + bf2f(a[5]) * w1.y + bf2f(a[6]) * w1.z + bf2f(a[7]) * w1.w;
  }
#pragma unroll
  for (int off = 32; off; off >>= 1) s += __shfl_xor(s, off);
  if (lane == 0) out[row] = 1.f / (1.f + expf(-(s + bt[0])));
}

// ---------------- program decode ----------------
__global__ __launch_bounds__(256) void decode_prog(const float* __restrict__ P_op,
                                                   const float* __restrict__ P_dst,
                                                   const float* __restrict__ P_s1,
                                                   const float* __restrict__ P_s2,
                                                   const float* __restrict__ P_imm,
                                                   const float* __restrict__ Plen,
                                                   float* __restrict__ prog,
                                                   float* __restrict__ plen, int BT) {
  const int i = blockIdx.x * 256 + threadIdx.x;
  if (i >= BT) return;
  const float* po = P_op + (size_t)i * 4;
  const float op = po[0] + 2.f * po[1] + 4.f * po[2] + 8.f * po[3];
  const float* pd = P_dst + (size_t)i * 3;
  const float dv = pd[0] + 2.f * pd[1] + 4.f * pd[2];
  const float* p1 = P_s1 + (size_t)i * 3;
  const float s1v = p1[0] + 2.f * p1[1] + 4.f * p1[2];
  const float* p2 = P_s2 + (size_t)i * 3;
  const float s2v = p2[0] + 2.f * p2[1] + 4.f * p2[2];
  const float* pi = P_imm + (size_t)i * 3;
  const float imv = pi[0] + 2.f * pi[1] + 4.f * pi[2];
  float* o = prog + (size_t)i * 5;
  o[0] = op; o[1] = dv; o[2] = s1v; o[3] = s2v; o[4] = imv;
  if ((i & 15) == 0) {
    const int b = i >> 4;
    const float* pl = Plen + (size_t)b * 4;
    plen[b] = pl[0] + 2.f * pl[1] + 4.f * pl[2] + 8.f * pl[3];
  }
}

// ---------------- per-(b,g) soft-VM scan ----------------
__global__ __launch_bounds__(256) void scan_kernel(const float* __restrict__ Rbits,
                                                   const float* __restrict__ prog,
                                                   const float* __restrict__ plen,
                                                   float* __restrict__ Rfinal, int B) {
  __shared__ float s_bits[16][128];
  __shared__ float s_prog[16][80];
  __shared__ float s_plen[16];
  const int tid = threadIdx.x;
  const int b0 = blockIdx.x * 16;
#pragma unroll
  for (int j = 0; j < 8; ++j) {
    const int f = tid + 256 * j;
    s_bits[f >> 7][f & 127] = Rbits[(size_t)(b0 + (f >> 7)) * 128 + (f & 127)];
  }
#pragma unroll
  for (int j = 0; j < 5; ++j) {
    const int f = tid + 256 * j;
    s_prog[f / 80][f % 80] = prog[(size_t)b0 * 80 + f];
  }
  if (tid < 16) s_plen[tid] = plen[b0 + tid];
  __syncthreads();

  const int lb = tid >> 4, g = tid & 15;
  const int bg = (b0 + lb) * 16 + g;

  uint32_t k2a, k2b;
  { uint32_t x0 = 0u, x1 = 1u; threefry2x32(0u, 42u, x0, x1); k2a = x0; k2b = x1; }
  uint32_t p0, p1;
  {
    uint32_t x0 = 0u, x1 = (uint32_t)bg * 2u;
    threefry2x32(k2a, k2b, x0, x1);
    p0 = (x0 ^ x1) & 127u;
  }
  {
    uint32_t x0 = 0u, x1 = (uint32_t)bg * 2u + 1u;
    threefry2x32(k2a, k2b, x0, x1);
    p1 = (x0 ^ x1) & 127u;
  }

  float R[8], M[8];
#pragma unroll
  for (int r = 0; r < 8; ++r) {
    float a = 0.f;
#pragma unroll
    for (int bit = 0; bit < 16; ++bit) {
      const int pos = r * 16 + bit;
      float v = s_bits[lb][pos];
      const bool flip = (g != 0) && ((int)p0 == pos || (int)p1 == pos);
      v = flip ? 1.0f - v : v;
      a = fmaf(v, (float)(1 << bit), a);
    }
    R[r] = a;
    M[r] = 0.f;
  }

  const float pl = s_plen[lb];
  for (int t = 0; t < 16; ++t) {
    const float op = s_prog[lb][t * 5 + 0];
    const float dst = s_prog[lb][t * 5 + 1];
    const float sa = s_prog[lb][t * 5 + 2];
    const float sb = s_prog[lb][t * 5 + 3];
    const float imm = s_prog[lb][t * 5 + 4];
    const float active = fminf(fmaxf(pl - (float)t, 0.f), 1.f);
    float r1 = 0.f, r2 = 0.f, m1 = 0.f, old = 0.f;
    float wd[8];
#pragma unroll
    for (int i = 0; i < 8; ++i) {
      const float w1 = fmaxf(1.f - fabsf(sa - (float)i), 0.f);
      const float w2 = fmaxf(1.f - fabsf(sb - (float)i), 0.f);
      wd[i] = fmaxf(1.f - fabsf(dst - (float)i), 0.f);
      r1 = fmaf(w1, R[i], r1);
      r2 = fmaf(w2, R[i], r2);
      m1 = fmaf(w1, M[i], m1);
      old = fmaf(wd[i], R[i], old);
    }
    float results[16];
    results[0] = old;               results[1] = r1 + r2;
    results[2] = r1 - r2;           results[3] = r1 * r2 * (1.f / 65536.f);
    results[4] = r1;                results[5] = imm;
    results[6] = r1 + imm;          results[7] = fmaxf(r1, r2);
    results[8] = fminf(r1, r2);     results[9] = -r1;
    results[10] = 0.5f * r1;        results[11] = r2;
    results[12] = m1;               results[13] = old;
    results[14] = fabsf(r1);        results[15] = old;
    float res = 0.f;
    const float pstore = fmaxf(1.f - fabsf(op - 13.f), 0.f);
#pragma unroll
    for (int o = 0; o < 16; ++o) res = fmaf(fmaxf(1.f - fabsf(op - (float)o), 0.f), results[o], res);
#pragma unroll
    for (int i = 0; i < 8; ++i) {
      R[i] = fmaf(active * wd[i], res - R[i], R[i]);
      M[i] = fmaf(active * pstore * wd[i], r1 - M[i], M[i]);
    }
  }

  float* outp = Rfinal + (size_t)bg * 8;
#pragma unroll
  for (int r = 0; r < 8; ++r) outp[r] = R[r];
}

// ---------------- reg_hidden = LN(R @ W_r2h + b) * g + b ; one wave per (b,g) ----------------
__global__ __launch_bounds__(256) void final_expand(const float* __restrict__ Rf,
                                                    const float* __restrict__ W,
                                                    const float* __restrict__ bias,
                                                    const float* __restrict__ gam,
                                                    const float* __restrict__ bet,
                                                    float* __restrict__ out) {
  const int lane = threadIdx.x & 63;
  const int bg = blockIdx.x * 4 + (threadIdx.x >> 6);
  const float* Rp = Rf + (size_t)bg * 8;
  float r[8];
#pragma unroll
  for (int i = 0; i < 8; ++i) r[i] = Rp[i];
  const int h0 = lane * 8;
  float x[8];
#pragma unroll
  for (int j = 0; j < 8; ++j) x[j] = bias[h0 + j];
#pragma unroll
  for (int reg = 0; reg < 8; ++reg) {
    const float4 wa = *reinterpret_cast<const float4*>(&W[reg * 512 + h0]);
    const float4 wb = *reinterpret_cast<const float4*>(&W[reg * 512 + h0 + 4]);
    x[0] = fmaf(r[reg], wa.x, x[0]); x[1] = fmaf(r[reg], wa.y, x[1]);
    x[2] = fmaf(r[reg], wa.z, x[2]); x[3] = fmaf(r[reg], wa.w, x[3]);
    x[4] = fmaf(r[reg], wb.x, x[4]); x[5] = fmaf(r[reg], wb.y, x[5]);
    x[6] = fmaf(r[reg], wb.z, x[6]); x[7] = fmaf(r[reg], wb.w, x[7]);
  }
  float s1 = 0.f, s2 = 0.f;
#pragma unroll
  for (int j = 0; j < 8; ++j) { s1 += x[j]; s2 = fmaf(x[j], x[j], s2); }
#pragma unroll
  for (int off = 32; off; off >>= 1) { s1 += __shfl_xor(s1, off); s2 += __shfl_xor(s2, off); }
  const float mean = s1 * (1.f / 512.f);
  const float var = s2 * (1.f / 512.f) - mean * mean;
  const float inv = rsqrtf(var + 1e-5f);
  float y[8];
#pragma unroll
  for (int j = 0; j < 8; ++j) y[j] = (x[j] - mean) * inv * gam[h0 + j] + bet[h0 + j];
  float* dst = out + (size_t)bg * 512 + h0;
  *reinterpret_cast<float4*>(dst) = make_float4(y[0], y[1], y[2], y[3]);
  *reinterpret_cast<float4*>(dst + 4) = make_float4(y[4], y[5], y[6], y[7]);
}

// ---------------- launch ----------------
extern "C" void kernel_launch(void* const* d_in, const int* in_sizes, int n_in,
                              void* d_out, int out_size, void* d_ws, size_t ws_size,
                              hipStream_t stream) {
  const float* z    = (const float*)d_in[0];
  const float* P_op = (const float*)d_in[1];
  const float* P_dst= (const float*)d_in[2];
  const float* P_s1 = (const float*)d_in[3];
  const float* P_s2 = (const float*)d_in[4];
  const float* P_imm= (const float*)d_in[5];
  const float* Plen = (const float*)d_in[6];
  const float* W1   = (const float*)d_in[8];
  const float* b1   = (const float*)d_in[9];
  const float* WR   = (const float*)d_in[10];
  const float* bR   = (const float*)d_in[11];
  const float* Wt   = (const float*)d_in[12];
  const float* bt   = (const float*)d_in[13];
  const float* W_r2h= (const float*)d_in[14];
  const float* b_r2h= (const float*)d_in[15];
  const float* ln_g = (const float*)d_in[16];
  const float* ln_b = (const float*)d_in[17];

  const int B = in_sizes[0] / 512;  // 8192
  float* out = (float*)d_out;
  unsigned short* h = (unsigned short*)out;            // B*1024 bf16, consumed before final_expand
  float* part    = out + (size_t)(1 << 25);            // 8 * B*128 f32 K-split partials
  float* thr_out = out + (size_t)B * 16 * 512;         // threshold output region

  float* ws = (float*)d_ws;
  float* Rbits  = ws;                                  // B*128
  float* prog   = Rbits + (size_t)B * 128;             // B*16*5
  float* plen   = prog + (size_t)B * 80;               // B
  float* Rfinal = plen + B;                            // B*16*8
  unsigned short* W1t = (unsigned short*)(Rfinal + (size_t)B * 128);  // 1024x512 bf16
  unsigned short* WRt = W1t + (size_t)1024 * 512;                     // 128x1024 bf16
  unsigned short* zb  = WRt + (size_t)128 * 1024;                     // B*512 bf16

  const dim3 blk(256);
  cast_bf16<<<dim3(B * 512 / 8 / 256), blk, 0, stream>>>(z, zb, B * 512 / 8);
  transpose_cast<<<dim3(640), blk, 0, stream>>>(W1, WR, W1t, WRt);
  // GEMM1: h = relu(z @ W1 + b1) -> bf16
  gemm_bf16<0><<<dim3(1024 / 128, B / 128, 1), blk, 0, stream>>>(zb, W1t, b1, h, 1024, 512, 512, 0);
  // GEMM2 partials: [8192x1024] x [1024x128], K split x8, f32 partials
  gemm_bf16<2><<<dim3(1, B / 128, 8), blk, 0, stream>>>(h, WRt, nullptr, part, 128, 1024, 128,
                                                        (size_t)B * 128);
  reduce_sig<<<dim3((B * 128 / 4 + 255) / 256), blk, 0, stream>>>(part, bR, Rbits, B * 128 / 4);
  thresh_kernel<<<dim3(B / 4), blk, 0, stream>>>(h, Wt, bt, thr_out, B);
  decode_prog<<<dim3((B * 16 + 255) / 256), blk, 0, stream>>>(P_op, P_dst, P_s1, P_s2, P_imm,
                                                              Plen, prog, plen, B * 16);
  scan_kernel<<<dim3(B / 16), blk, 0, stream>>>(Rbits, prog, plen, Rfinal, B);
  final_expand<<<dim3(B * 16 / 4), blk, 0, stream>>>(Rfinal, W_r2h, b_r2h, ln_g, ln_b, out);
}

// Round 6
// 128.962 us; speedup vs baseline: 2.4222x; 1.4938x over previous
//
#include <hip/hip_runtime.h>
#include <stdint.h>

typedef __attribute__((ext_vector_type(8))) short short8;
typedef __attribute__((ext_vector_type(4))) float f32x4;
typedef __attribute__((ext_vector_type(8))) unsigned short ushort8;
typedef __attribute__((ext_vector_type(4))) unsigned short ushort4v;

__device__ __forceinline__ unsigned short f2bf(float f) {
  uint32_t u = __float_as_uint(f);
  uint32_t r = (u + 0x7fffu + ((u >> 16) & 1u)) >> 16;  // RNE
  return (unsigned short)r;
}
__device__ __forceinline__ float bf2f(unsigned short v) {
  return __uint_as_float(((uint32_t)v) << 16);
}

// ---------------- Threefry-2x32-20 (exact JAX partitionable semantics) ----------------
__device__ __forceinline__ uint32_t rotl32(uint32_t v, int d) { return (v << d) | (v >> (32 - d)); }

__device__ __forceinline__ void threefry2x32(uint32_t k0, uint32_t k1, uint32_t& x0, uint32_t& x1) {
  const uint32_t ks2 = k0 ^ k1 ^ 0x1BD11BDAu;
  x0 += k0; x1 += k1;
  x0 += x1; x1 = rotl32(x1, 13); x1 ^= x0;
  x0 += x1; x1 = rotl32(x1, 15); x1 ^= x0;
  x0 += x1; x1 = rotl32(x1, 26); x1 ^= x0;
  x0 += x1; x1 = rotl32(x1, 6);  x1 ^= x0;
  x0 += k1; x1 += ks2 + 1u;
  x0 += x1; x1 = rotl32(x1, 17); x1 ^= x0;
  x0 += x1; x1 = rotl32(x1, 29); x1 ^= x0;
  x0 += x1; x1 = rotl32(x1, 16); x1 ^= x0;
  x0 += x1; x1 = rotl32(x1, 24); x1 ^= x0;
  x0 += ks2; x1 += k0 + 2u;
  x0 += x1; x1 = rotl32(x1, 13); x1 ^= x0;
  x0 += x1; x1 = rotl32(x1, 15); x1 ^= x0;
  x0 += x1; x1 = rotl32(x1, 26); x1 ^= x0;
  x0 += x1; x1 = rotl32(x1, 6);  x1 ^= x0;
  x0 += k0; x1 += k1 + 3u;
  x0 += x1; x1 = rotl32(x1, 17); x1 ^= x0;
  x0 += x1; x1 = rotl32(x1, 29); x1 ^= x0;
  x0 += x1; x1 = rotl32(x1, 16); x1 ^= x0;
  x0 += x1; x1 = rotl32(x1, 24); x1 ^= x0;
  x0 += k1; x1 += ks2 + 4u;
  x0 += x1; x1 = rotl32(x1, 13); x1 ^= x0;
  x0 += x1; x1 = rotl32(x1, 15); x1 ^= x0;
  x0 += x1; x1 = rotl32(x1, 26); x1 ^= x0;
  x0 += x1; x1 = rotl32(x1, 6);  x1 ^= x0;
  x0 += ks2; x1 += k0 + 5u;
}

// ---------------- z (f32) -> bf16 ----------------
__global__ __launch_bounds__(256) void cast_bf16(const float* __restrict__ in,
                                                 unsigned short* __restrict__ o, int n8) {
  const int i = blockIdx.x * 256 + threadIdx.x;
  if (i >= n8) return;
  const float4 a = reinterpret_cast<const float4*>(in)[i * 2];
  const float4 b = reinterpret_cast<const float4*>(in)[i * 2 + 1];
  ushort8 u;
  u[0] = f2bf(a.x); u[1] = f2bf(a.y); u[2] = f2bf(a.z); u[3] = f2bf(a.w);
  u[4] = f2bf(b.x); u[5] = f2bf(b.y); u[6] = f2bf(b.z); u[7] = f2bf(b.w);
  reinterpret_cast<ushort8*>(o)[i] = u;
}

// ---------------- transpose + cast weights ----------------
__global__ __launch_bounds__(256) void transpose_cast(const float* __restrict__ W1,
                                                      const float* __restrict__ WR,
                                                      unsigned short* __restrict__ W1t,
                                                      unsigned short* __restrict__ WRt) {
  __shared__ float t[32][33];
  const int tid = threadIdx.x;
  const float* src; unsigned short* dst; int N, K, k0, n0;
  if (blockIdx.x < 512) {
    src = W1; dst = W1t; N = 1024; K = 512;
    k0 = (blockIdx.x & 15) * 32; n0 = (blockIdx.x >> 4) * 32;
  } else {
    const int b2 = blockIdx.x - 512;
    src = WR; dst = WRt; N = 128; K = 1024;
    k0 = (b2 & 31) * 32; n0 = (b2 >> 5) * 32;
  }
  {
    const int row = tid >> 3, c4 = (tid & 7) * 4;
    const float4 v = *reinterpret_cast<const float4*>(&src[(size_t)(k0 + row) * N + n0 + c4]);
    t[row][c4] = v.x; t[row][c4 + 1] = v.y; t[row][c4 + 2] = v.z; t[row][c4 + 3] = v.w;
  }
  __syncthreads();
  {
    const int n = tid >> 3, k4 = (tid & 7) * 4;
    ushort4v o;
    o.x = f2bf(t[k4 + 0][n]); o.y = f2bf(t[k4 + 1][n]);
    o.z = f2bf(t[k4 + 2][n]); o.w = f2bf(t[k4 + 3][n]);
    *reinterpret_cast<ushort4v*>(&dst[(size_t)(n0 + n) * K + k0 + k4]) = o;
  }
}

// ---------------- fused GEMM1 + GEMM2-slice ----------------
// Block (bx, by): GEMM1 tile h[by*128..+128][bx*128..+128] = relu(zb @ W1t + b1) -> global h (bf16)
// then GEMM2 partial slice bx: part[bx][rows][0..128] = h_tile @ WRt[:, bx*128..+128]^T
__global__ __launch_bounds__(256) void gemm_fused(const unsigned short* __restrict__ zb,
                                                  const unsigned short* __restrict__ W1t,
                                                  const float* __restrict__ b1,
                                                  const unsigned short* __restrict__ WRt,
                                                  unsigned short* __restrict__ h,
                                                  float* __restrict__ part, int B) {
  __shared__ __align__(16) char smem[34816];
  auto As = reinterpret_cast<unsigned short (*)[56]>(smem);           // phase 1: [128][56]
  auto Bs = reinterpret_cast<unsigned short (*)[56]>(smem + 14336);   // phase 1: [128][56]
  auto H2 = reinterpret_cast<unsigned short (*)[136]>(smem);          // phase 2: [128][136]

  const int tid = threadIdx.x;
  const int lane = tid & 63, wave = tid >> 6;
  const int wm = wave >> 1, wn = wave & 1;
  const int bx = blockIdx.x, bm = blockIdx.y * 128, bn = bx * 128;

  f32x4 acc[4][4];
#pragma unroll
  for (int i = 0; i < 4; ++i)
#pragma unroll
    for (int j = 0; j < 4; ++j) acc[i][j] = (f32x4)0.f;

  const int sm = tid >> 1, skh = (tid & 1) * 16;
  const int fr = lane & 15, kc = (lane >> 4) * 8;
  const int lr = (lane >> 4) * 4, lc = lane & 15;

  // ---- phase 1: GEMM1 over K=512 ----
  for (int k0 = 0; k0 < 512; k0 += 32) {
    {
      const unsigned short* ap = &zb[(size_t)(bm + sm) * 512 + k0 + skh];
      *reinterpret_cast<ushort8*>(&As[sm][skh]) = *reinterpret_cast<const ushort8*>(ap);
      *reinterpret_cast<ushort8*>(&As[sm][skh + 8]) = *reinterpret_cast<const ushort8*>(ap + 8);
    }
    {
      const unsigned short* bp = &W1t[(size_t)(bn + sm) * 512 + k0 + skh];
      *reinterpret_cast<ushort8*>(&Bs[sm][skh]) = *reinterpret_cast<const ushort8*>(bp);
      *reinterpret_cast<ushort8*>(&Bs[sm][skh + 8]) = *reinterpret_cast<const ushort8*>(bp + 8);
    }
    __syncthreads();
    short8 af[4], bfv[4];
#pragma unroll
    for (int f = 0; f < 4; ++f)
      af[f] = *reinterpret_cast<const short8*>(&As[wm * 64 + f * 16 + fr][kc]);
#pragma unroll
    for (int f = 0; f < 4; ++f)
      bfv[f] = *reinterpret_cast<const short8*>(&Bs[wn * 64 + f * 16 + fr][kc]);
#pragma unroll
    for (int fm = 0; fm < 4; ++fm)
#pragma unroll
      for (int fn = 0; fn < 4; ++fn)
        acc[fm][fn] = __builtin_amdgcn_mfma_f32_16x16x32_bf16(af[fm], bfv[fn], acc[fm][fn], 0, 0, 0);
    __syncthreads();
  }

  // ---- epilogue: h_tile = relu(acc + b1) bf16 -> LDS H2 (As/Bs dead after last sync) ----
#pragma unroll
  for (int fn = 0; fn < 4; ++fn) {
    const int col_l = wn * 64 + fn * 16 + lc;
    const float bv = b1[bn + col_l];
#pragma unroll
    for (int fm = 0; fm < 4; ++fm) {
      const int row_l0 = wm * 64 + fm * 16 + lr;
#pragma unroll
      for (int r = 0; r < 4; ++r)
        H2[row_l0 + r][col_l] = f2bf(fmaxf(acc[fm][fn][r] + bv, 0.f));
    }
  }
  __syncthreads();

  // copy H2 -> global h (vectorized, coalesced)
  {
    const int row = tid >> 1, c0 = (tid & 1) * 64;
    unsigned short* hp = &h[(size_t)(bm + row) * 1024 + bn + c0];
#pragma unroll
    for (int j = 0; j < 8; ++j)
      *reinterpret_cast<ushort8*>(hp + j * 8) = *reinterpret_cast<const ushort8*>(&H2[row][c0 + j * 8]);
  }

  // ---- phase 2: GEMM2 slice: acc2 = h_tile @ WRt[:, bn..bn+128]^T ----
  f32x4 acc2[4][4];
#pragma unroll
  for (int i = 0; i < 4; ++i)
#pragma unroll
    for (int j = 0; j < 4; ++j) acc2[i][j] = (f32x4)0.f;

#pragma unroll
  for (int ks = 0; ks < 4; ++ks) {
    short8 af2[4], bf2v[4];
#pragma unroll
    for (int fm = 0; fm < 4; ++fm)
      af2[fm] = *reinterpret_cast<const short8*>(&H2[wm * 64 + fm * 16 + fr][ks * 32 + kc]);
#pragma unroll
    for (int fn = 0; fn < 4; ++fn)
      bf2v[fn] = *reinterpret_cast<const short8*>(
          &WRt[(size_t)(wn * 64 + fn * 16 + fr) * 1024 + bn + ks * 32 + kc]);
#pragma unroll
    for (int fm = 0; fm < 4; ++fm)
#pragma unroll
      for (int fn = 0; fn < 4; ++fn)
        acc2[fm][fn] = __builtin_amdgcn_mfma_f32_16x16x32_bf16(af2[fm], bf2v[fn], acc2[fm][fn], 0, 0, 0);
  }

  float* pp = part + (size_t)bx * B * 128;
#pragma unroll
  for (int fn = 0; fn < 4; ++fn) {
    const int col = wn * 64 + fn * 16 + lc;
#pragma unroll
    for (int fm = 0; fm < 4; ++fm) {
      const int row0 = bm + wm * 64 + fm * 16 + lr;
#pragma unroll
      for (int r = 0; r < 4; ++r)
        pp[(size_t)(row0 + r) * 128 + col] = acc2[fm][fn][r];
    }
  }
}

// ---------------- sum 8 K-split partials + bias -> sigmoid -> Rbits ----------------
__global__ __launch_bounds__(256) void reduce_sig(const float* __restrict__ part,
                                                  const float* __restrict__ bR,
                                                  float* __restrict__ out, int total4) {
  const int i = blockIdx.x * 256 + threadIdx.x;
  if (i >= total4) return;
  const float4* p = reinterpret_cast<const float4*>(part);
  float4 s = p[i];
#pragma unroll
  for (int j = 1; j < 8; ++j) {
    const float4 q = p[i + (size_t)j * total4];
    s.x += q.x; s.y += q.y; s.z += q.z; s.w += q.w;
  }
  const int col = (i * 4) & 127;
  const float4 bb = *reinterpret_cast<const float4*>(&bR[col]);
  float4 o;
  o.x = 1.f / (1.f + expf(-(s.x + bb.x)));
  o.y = 1.f / (1.f + expf(-(s.y + bb.y)));
  o.z = 1.f / (1.f + expf(-(s.z + bb.z)));
  o.w = 1.f / (1.f + expf(-(s.w + bb.w)));
  reinterpret_cast<float4*>(out)[i] = o;
}

// ---------------- threshold = sigmoid(h @ Wt + bt), h bf16 ----------------
__global__ __launch_bounds__(256) void thresh_kernel(const unsigned short* __restrict__ h,
                                                     const float* __restrict__ Wt,
                                                     const float* __restrict__ bt,
                                                     float* __restrict__ out, int B) {
  const int lane = threadIdx.x & 63;
  const int row = blockIdx.x * 4 + (threadIdx.x >> 6);
  if (row >= B) return;
  const unsigned short* hr = h + (size_t)row * 1024;
  float s = 0.f;
#pragma unroll
  for (int it = 0; it < 2; ++it) {
    const int k = (lane + it * 64) * 8;
    const ushort8 a = *reinterpret_cast<const ushort8*>(&hr[k]);
    const float4 w0 = *reinterpret_cast<const float4*>(&Wt[k]);
    const float4 w1 = *reinterpret_cast<const float4*>(&Wt[k + 4]);
    s += bf2f(a[0]) * w0.x + bf2f(a[1]) * w0.y + bf2f(a[2]) * w0.z + bf2f(a[3]) * w0.w;
    s += bf2f(a[4]) * w1.x + bf2f(a[5]) * w1.y + bf2f(a[6]) * w1.z + bf2f(a[7]) * w1.w;
  }
#pragma unroll
  for (int off = 32; off; off >>= 1) s += __shfl_xor(s, off);
  if (lane == 0) out[row] = 1.f / (1.f + expf(-(s + bt[0])));
}

// ---------------- program decode ----------------
__global__ __launch_bounds__(256) void decode_prog(const float* __restrict__ P_op,
                                                   const float* __restrict__ P_dst,
                                                   const float* __restrict__ P_s1,
                                                   const float* __restrict__ P_s2,
                                                   const float* __restrict__ P_imm,
                                                   const float* __restrict__ Plen,
                                                   float* __restrict__ prog,
                                                   float* __restrict__ plen, int BT) {
  const int i = blockIdx.x * 256 + threadIdx.x;
  if (i >= BT) return;
  const float* po = P_op + (size_t)i * 4;
  const float op = po[0] + 2.f * po[1] + 4.f * po[2] + 8.f * po[3];
  const float* pd = P_dst + (size_t)i * 3;
  const float dv = pd[0] + 2.f * pd[1] + 4.f * pd[2];
  const float* p1 = P_s1 + (size_t)i * 3;
  const float s1v = p1[0] + 2.f * p1[1] + 4.f * p1[2];
  const float* p2 = P_s2 + (size_t)i * 3;
  const float s2v = p2[0] + 2.f * p2[1] + 4.f * p2[2];
  const float* pi = P_imm + (size_t)i * 3;
  const float imv = pi[0] + 2.f * pi[1] + 4.f * pi[2];
  float* o = prog + (size_t)i * 5;
  o[0] = op; o[1] = dv; o[2] = s1v; o[3] = s2v; o[4] = imv;
  if ((i & 15) == 0) {
    const int b = i >> 4;
    const float* pl = Plen + (size_t)b * 4;
    plen[b] = pl[0] + 2.f * pl[1] + 4.f * pl[2] + 8.f * pl[3];
  }
}

// ---------------- per-(b,g) soft-VM scan ----------------
__global__ __launch_bounds__(256) void scan_kernel(const float* __restrict__ Rbits,
                                                   const float* __restrict__ prog,
                                                   const float* __restrict__ plen,
                                                   float* __restrict__ Rfinal, int B) {
  __shared__ float s_bits[16][128];
  __shared__ float s_prog[16][80];
  __shared__ float s_plen[16];
  const int tid = threadIdx.x;
  const int b0 = blockIdx.x * 16;
#pragma unroll
  for (int j = 0; j < 8; ++j) {
    const int f = tid + 256 * j;
    s_bits[f >> 7][f & 127] = Rbits[(size_t)(b0 + (f >> 7)) * 128 + (f & 127)];
  }
#pragma unroll
  for (int j = 0; j < 5; ++j) {
    const int f = tid + 256 * j;
    s_prog[f / 80][f % 80] = prog[(size_t)b0 * 80 + f];
  }
  if (tid < 16) s_plen[tid] = plen[b0 + tid];
  __syncthreads();

  const int lb = tid >> 4, g = tid & 15;
  const int bg = (b0 + lb) * 16 + g;

  uint32_t k2a, k2b;
  { uint32_t x0 = 0u, x1 = 1u; threefry2x32(0u, 42u, x0, x1); k2a = x0; k2b = x1; }
  uint32_t p0, p1;
  {
    uint32_t x0 = 0u, x1 = (uint32_t)bg * 2u;
    threefry2x32(k2a, k2b, x0, x1);
    p0 = (x0 ^ x1) & 127u;
  }
  {
    uint32_t x0 = 0u, x1 = (uint32_t)bg * 2u + 1u;
    threefry2x32(k2a, k2b, x0, x1);
    p1 = (x0 ^ x1) & 127u;
  }

  float R[8], M[8];
#pragma unroll
  for (int r = 0; r < 8; ++r) {
    float a = 0.f;
#pragma unroll
    for (int bit = 0; bit < 16; ++bit) {
      const int pos = r * 16 + bit;
      float v = s_bits[lb][pos];
      const bool flip = (g != 0) && ((int)p0 == pos || (int)p1 == pos);
      v = flip ? 1.0f - v : v;
      a = fmaf(v, (float)(1 << bit), a);
    }
    R[r] = a;
    M[r] = 0.f;
  }

  const float pl = s_plen[lb];
  for (int t = 0; t < 16; ++t) {
    const float op = s_prog[lb][t * 5 + 0];
    const float dst = s_prog[lb][t * 5 + 1];
    const float sa = s_prog[lb][t * 5 + 2];
    const float sb = s_prog[lb][t * 5 + 3];
    const float imm = s_prog[lb][t * 5 + 4];
    const float active = fminf(fmaxf(pl - (float)t, 0.f), 1.f);
    float r1 = 0.f, r2 = 0.f, m1 = 0.f, old = 0.f;
    float wd[8];
#pragma unroll
    for (int i = 0; i < 8; ++i) {
      const float w1 = fmaxf(1.f - fabsf(sa - (float)i), 0.f);
      const float w2 = fmaxf(1.f - fabsf(sb - (float)i), 0.f);
      wd[i] = fmaxf(1.f - fabsf(dst - (float)i), 0.f);
      r1 = fmaf(w1, R[i], r1);
      r2 = fmaf(w2, R[i], r2);
      m1 = fmaf(w1, M[i], m1);
      old = fmaf(wd[i], R[i], old);
    }
    float results[16];
    results[0] = old;               results[1] = r1 + r2;
    results[2] = r1 - r2;           results[3] = r1 * r2 * (1.f / 65536.f);
    results[4] = r1;                results[5] = imm;
    results[6] = r1 + imm;          results[7] = fmaxf(r1, r2);
    results[8] = fminf(r1, r2);     results[9] = -r1;
    results[10] = 0.5f * r1;        results[11] = r2;
    results[12] = m1;               results[13] = old;
    results[14] = fabsf(r1);        results[15] = old;
    float res = 0.f;
    const float pstore = fmaxf(1.f - fabsf(op - 13.f), 0.f);
#pragma unroll
    for (int o = 0; o < 16; ++o) res = fmaf(fmaxf(1.f - fabsf(op - (float)o), 0.f), results[o], res);
#pragma unroll
    for (int i = 0; i < 8; ++i) {
      R[i] = fmaf(active * wd[i], res - R[i], R[i]);
      M[i] = fmaf(active * pstore * wd[i], r1 - M[i], M[i]);
    }
  }

  float* outp = Rfinal + (size_t)bg * 8;
#pragma unroll
  for (int r = 0; r < 8; ++r) outp[r] = R[r];
}

// ---------------- expand: W fragment in registers, each wave loops 32 rows ----------------
__global__ __launch_bounds__(256) void final_expand2(const float* __restrict__ Rf,
                                                     const float* __restrict__ W,
                                                     const float* __restrict__ bias,
                                                     const float* __restrict__ gam,
                                                     const float* __restrict__ bet,
                                                     float* __restrict__ out, int rowsPerWave) {
  const int lane = threadIdx.x & 63;
  const int w = blockIdx.x * 4 + (threadIdx.x >> 6);
  const int h0 = lane * 8;

  float wreg[8][8];
#pragma unroll
  for (int reg = 0; reg < 8; ++reg) {
    const float4 wa = *reinterpret_cast<const float4*>(&W[reg * 512 + h0]);
    const float4 wb = *reinterpret_cast<const float4*>(&W[reg * 512 + h0 + 4]);
    wreg[reg][0] = wa.x; wreg[reg][1] = wa.y; wreg[reg][2] = wa.z; wreg[reg][3] = wa.w;
    wreg[reg][4] = wb.x; wreg[reg][5] = wb.y; wreg[reg][6] = wb.z; wreg[reg][7] = wb.w;
  }
  float bi[8], ga[8], be[8];
  {
    const float4 a = *reinterpret_cast<const float4*>(&bias[h0]);
    const float4 b = *reinterpret_cast<const float4*>(&bias[h0 + 4]);
    bi[0] = a.x; bi[1] = a.y; bi[2] = a.z; bi[3] = a.w; bi[4] = b.x; bi[5] = b.y; bi[6] = b.z; bi[7] = b.w;
    const float4 c = *reinterpret_cast<const float4*>(&gam[h0]);
    const float4 d = *reinterpret_cast<const float4*>(&gam[h0 + 4]);
    ga[0] = c.x; ga[1] = c.y; ga[2] = c.z; ga[3] = c.w; ga[4] = d.x; ga[5] = d.y; ga[6] = d.z; ga[7] = d.w;
    const float4 e = *reinterpret_cast<const float4*>(&bet[h0]);
    const float4 f = *reinterpret_cast<const float4*>(&bet[h0 + 4]);
    be[0] = e.x; be[1] = e.y; be[2] = e.z; be[3] = e.w; be[4] = f.x; be[5] = f.y; be[6] = f.z; be[7] = f.w;
  }

  const int r0 = w * rowsPerWave;
  for (int i = 0; i < rowsPerWave; ++i) {
    const int row = r0 + i;
    const float4 ra = *reinterpret_cast<const float4*>(&Rf[(size_t)row * 8]);
    const float4 rb = *reinterpret_cast<const float4*>(&Rf[(size_t)row * 8 + 4]);
    const float r[8] = {ra.x, ra.y, ra.z, ra.w, rb.x, rb.y, rb.z, rb.w};
    float x[8];
#pragma unroll
    for (int j = 0; j < 8; ++j) x[j] = bi[j];
#pragma unroll
    for (int reg = 0; reg < 8; ++reg)
#pragma unroll
      for (int j = 0; j < 8; ++j) x[j] = fmaf(r[reg], wreg[reg][j], x[j]);
    float s1 = 0.f, s2 = 0.f;
#pragma unroll
    for (int j = 0; j < 8; ++j) { s1 += x[j]; s2 = fmaf(x[j], x[j], s2); }
#pragma unroll
    for (int off = 32; off; off >>= 1) { s1 += __shfl_xor(s1, off); s2 += __shfl_xor(s2, off); }
    const float mean = s1 * (1.f / 512.f);
    const float var = s2 * (1.f / 512.f) - mean * mean;
    const float inv = rsqrtf(var + 1e-5f);
    float y[8];
#pragma unroll
    for (int j = 0; j < 8; ++j) y[j] = (x[j] - mean) * inv * ga[j] + be[j];
    float* dst = out + (size_t)row * 512 + h0;
    *reinterpret_cast<float4*>(dst) = make_float4(y[0], y[1], y[2], y[3]);
    *reinterpret_cast<float4*>(dst + 4) = make_float4(y[4], y[5], y[6], y[7]);
  }
}

// ---------------- launch ----------------
extern "C" void kernel_launch(void* const* d_in, const int* in_sizes, int n_in,
                              void* d_out, int out_size, void* d_ws, size_t ws_size,
                              hipStream_t stream) {
  const float* z    = (const float*)d_in[0];
  const float* P_op = (const float*)d_in[1];
  const float* P_dst= (const float*)d_in[2];
  const float* P_s1 = (const float*)d_in[3];
  const float* P_s2 = (const float*)d_in[4];
  const float* P_imm= (const float*)d_in[5];
  const float* Plen = (const float*)d_in[6];
  const float* W1   = (const float*)d_in[8];
  const float* b1   = (const float*)d_in[9];
  const float* WR   = (const float*)d_in[10];
  const float* bR   = (const float*)d_in[11];
  const float* Wt   = (const float*)d_in[12];
  const float* bt   = (const float*)d_in[13];
  const float* W_r2h= (const float*)d_in[14];
  const float* b_r2h= (const float*)d_in[15];
  const float* ln_g = (const float*)d_in[16];
  const float* ln_b = (const float*)d_in[17];

  const int B = in_sizes[0] / 512;  // 8192
  float* out = (float*)d_out;
  unsigned short* h = (unsigned short*)out;            // B*1024 bf16, consumed before final_expand2
  float* part    = out + (size_t)(1 << 25);            // 8 * B*128 f32 K-split partials
  float* thr_out = out + (size_t)B * 16 * 512;         // threshold output region

  float* ws = (float*)d_ws;
  float* Rbits  = ws;                                  // B*128
  float* prog   = Rbits + (size_t)B * 128;             // B*16*5
  float* plen   = prog + (size_t)B * 80;               // B
  float* Rfinal = plen + B;                            // B*16*8
  unsigned short* W1t = (unsigned short*)(Rfinal + (size_t)B * 128);  // 1024x512 bf16
  unsigned short* WRt = W1t + (size_t)1024 * 512;                     // 128x1024 bf16
  unsigned short* zb  = WRt + (size_t)128 * 1024;                     // B*512 bf16

  const dim3 blk(256);
  cast_bf16<<<dim3(B * 512 / 8 / 256), blk, 0, stream>>>(z, zb, B * 512 / 8);
  transpose_cast<<<dim3(640), blk, 0, stream>>>(W1, WR, W1t, WRt);
  gemm_fused<<<dim3(8, B / 128), blk, 0, stream>>>(zb, W1t, b1, WRt, h, part, B);
  reduce_sig<<<dim3((B * 128 / 4 + 255) / 256), blk, 0, stream>>>(part, bR, Rbits, B * 128 / 4);
  thresh_kernel<<<dim3(B / 4), blk, 0, stream>>>(h, Wt, bt, thr_out, B);
  decode_prog<<<dim3((B * 16 + 255) / 256), blk, 0, stream>>>(P_op, P_dst, P_s1, P_s2, P_imm,
                                                              Plen, prog, plen, B * 16);
  scan_kernel<<<dim3(B / 16), blk, 0, stream>>>(Rbits, prog, plen, Rfinal, B);
  final_expand2<<<dim3(B * 16 / 4 / 32), blk, 0, stream>>>(Rfinal, W_r2h, b_r2h, ln_g, ln_b, out,
                                                           32);
}

// Round 7
// 120.933 us; speedup vs baseline: 2.5830x; 1.0664x over previous
//
#include <hip/hip_runtime.h>
#include <stdint.h>

typedef __attribute__((ext_vector_type(8))) short short8;
typedef __attribute__((ext_vector_type(4))) float f32x4;
typedef __attribute__((ext_vector_type(8))) unsigned short ushort8;
typedef __attribute__((ext_vector_type(4))) unsigned short ushort4v;

__device__ __forceinline__ unsigned short f2bf(float f) {
  uint32_t u = __float_as_uint(f);
  uint32_t r = (u + 0x7fffu + ((u >> 16) & 1u)) >> 16;  // RNE
  return (unsigned short)r;
}
__device__ __forceinline__ float bf2f(unsigned short v) {
  return __uint_as_float(((uint32_t)v) << 16);
}

// ---------------- Threefry-2x32-20 (exact JAX partitionable semantics) ----------------
__device__ __forceinline__ uint32_t rotl32(uint32_t v, int d) { return (v << d) | (v >> (32 - d)); }

__device__ __forceinline__ void threefry2x32(uint32_t k0, uint32_t k1, uint32_t& x0, uint32_t& x1) {
  const uint32_t ks2 = k0 ^ k1 ^ 0x1BD11BDAu;
  x0 += k0; x1 += k1;
  x0 += x1; x1 = rotl32(x1, 13); x1 ^= x0;
  x0 += x1; x1 = rotl32(x1, 15); x1 ^= x0;
  x0 += x1; x1 = rotl32(x1, 26); x1 ^= x0;
  x0 += x1; x1 = rotl32(x1, 6);  x1 ^= x0;
  x0 += k1; x1 += ks2 + 1u;
  x0 += x1; x1 = rotl32(x1, 17); x1 ^= x0;
  x0 += x1; x1 = rotl32(x1, 29); x1 ^= x0;
  x0 += x1; x1 = rotl32(x1, 16); x1 ^= x0;
  x0 += x1; x1 = rotl32(x1, 24); x1 ^= x0;
  x0 += ks2; x1 += k0 + 2u;
  x0 += x1; x1 = rotl32(x1, 13); x1 ^= x0;
  x0 += x1; x1 = rotl32(x1, 15); x1 ^= x0;
  x0 += x1; x1 = rotl32(x1, 26); x1 ^= x0;
  x0 += x1; x1 = rotl32(x1, 6);  x1 ^= x0;
  x0 += k0; x1 += k1 + 3u;
  x0 += x1; x1 = rotl32(x1, 17); x1 ^= x0;
  x0 += x1; x1 = rotl32(x1, 29); x1 ^= x0;
  x0 += x1; x1 = rotl32(x1, 16); x1 ^= x0;
  x0 += x1; x1 = rotl32(x1, 24); x1 ^= x0;
  x0 += k1; x1 += ks2 + 4u;
  x0 += x1; x1 = rotl32(x1, 13); x1 ^= x0;
  x0 += x1; x1 = rotl32(x1, 15); x1 ^= x0;
  x0 += x1; x1 = rotl32(x1, 26); x1 ^= x0;
  x0 += x1; x1 = rotl32(x1, 6);  x1 ^= x0;
  x0 += ks2; x1 += k0 + 5u;
}

// ---------------- prep: cast z->bf16 | transpose+cast W1,WR | decode prog ----------------
// blocks [0,2048): cast; [2048,2688): transpose; [2688,3200): decode
__global__ __launch_bounds__(256) void prep_kernel(const float* __restrict__ z,
                                                   unsigned short* __restrict__ zb, int n8,
                                                   const float* __restrict__ W1,
                                                   const float* __restrict__ WR,
                                                   unsigned short* __restrict__ W1t,
                                                   unsigned short* __restrict__ WRt,
                                                   const float* __restrict__ P_op,
                                                   const float* __restrict__ P_dst,
                                                   const float* __restrict__ P_s1,
                                                   const float* __restrict__ P_s2,
                                                   const float* __restrict__ P_imm,
                                                   const float* __restrict__ Plen,
                                                   float* __restrict__ prog,
                                                   float* __restrict__ plen, int BT) {
  __shared__ float t[32][33];
  const int tid = threadIdx.x;
  const int bx = blockIdx.x;
  if (bx < 2048) {                       // ---- cast z -> bf16 ----
    const int i = bx * 256 + tid;
    if (i >= n8) return;
    const float4 a = reinterpret_cast<const float4*>(z)[i * 2];
    const float4 b = reinterpret_cast<const float4*>(z)[i * 2 + 1];
    ushort8 u;
    u[0] = f2bf(a.x); u[1] = f2bf(a.y); u[2] = f2bf(a.z); u[3] = f2bf(a.w);
    u[4] = f2bf(b.x); u[5] = f2bf(b.y); u[6] = f2bf(b.z); u[7] = f2bf(b.w);
    reinterpret_cast<ushort8*>(zb)[i] = u;
  } else if (bx < 2688) {                // ---- transpose + cast weights ----
    const int b = bx - 2048;
    const float* src; unsigned short* dst; int N, K, k0, n0;
    if (b < 512) {
      src = W1; dst = W1t; N = 1024; K = 512;
      k0 = (b & 15) * 32; n0 = (b >> 4) * 32;
    } else {
      const int b2 = b - 512;
      src = WR; dst = WRt; N = 128; K = 1024;
      k0 = (b2 & 31) * 32; n0 = (b2 >> 5) * 32;
    }
    {
      const int row = tid >> 3, c4 = (tid & 7) * 4;
      const float4 v = *reinterpret_cast<const float4*>(&src[(size_t)(k0 + row) * N + n0 + c4]);
      t[row][c4] = v.x; t[row][c4 + 1] = v.y; t[row][c4 + 2] = v.z; t[row][c4 + 3] = v.w;
    }
    __syncthreads();
    {
      const int n = tid >> 3, k4 = (tid & 7) * 4;
      ushort4v o;
      o.x = f2bf(t[k4 + 0][n]); o.y = f2bf(t[k4 + 1][n]);
      o.z = f2bf(t[k4 + 2][n]); o.w = f2bf(t[k4 + 3][n]);
      *reinterpret_cast<ushort4v*>(&dst[(size_t)(n0 + n) * K + k0 + k4]) = o;
    }
  } else {                               // ---- decode prog ----
    const int i = (bx - 2688) * 256 + tid;
    if (i >= BT) return;
    const float* po = P_op + (size_t)i * 4;
    const float op = po[0] + 2.f * po[1] + 4.f * po[2] + 8.f * po[3];
    const float* pd = P_dst + (size_t)i * 3;
    const float dv = pd[0] + 2.f * pd[1] + 4.f * pd[2];
    const float* p1 = P_s1 + (size_t)i * 3;
    const float s1v = p1[0] + 2.f * p1[1] + 4.f * p1[2];
    const float* p2 = P_s2 + (size_t)i * 3;
    const float s2v = p2[0] + 2.f * p2[1] + 4.f * p2[2];
    const float* pi = P_imm + (size_t)i * 3;
    const float imv = pi[0] + 2.f * pi[1] + 4.f * pi[2];
    float* o = prog + (size_t)i * 5;
    o[0] = op; o[1] = dv; o[2] = s1v; o[3] = s2v; o[4] = imv;
    if ((i & 15) == 0) {
      const int b = i >> 4;
      const float* pl = Plen + (size_t)b * 4;
      plen[b] = pl[0] + 2.f * pl[1] + 4.f * pl[2] + 8.f * pl[3];
    }
  }
}

// ---------------- fused GEMM1 + GEMM2-slice, BK=64 ----------------
__global__ __launch_bounds__(256) void gemm_fused(const unsigned short* __restrict__ zb,
                                                  const unsigned short* __restrict__ W1t,
                                                  const float* __restrict__ b1,
                                                  const unsigned short* __restrict__ WRt,
                                                  unsigned short* __restrict__ h,
                                                  float* __restrict__ part, int B) {
  __shared__ __align__(16) char smem[36864];
  auto As = reinterpret_cast<unsigned short (*)[72]>(smem);           // phase 1: [128][72]
  auto Bs = reinterpret_cast<unsigned short (*)[72]>(smem + 18432);   // phase 1: [128][72]
  auto H2 = reinterpret_cast<unsigned short (*)[136]>(smem);          // phase 2: [128][136]

  const int tid = threadIdx.x;
  const int lane = tid & 63, wave = tid >> 6;
  const int wm = wave >> 1, wn = wave & 1;
  const int bx = blockIdx.x, bm = blockIdx.y * 128, bn = bx * 128;

  f32x4 acc[4][4];
#pragma unroll
  for (int i = 0; i < 4; ++i)
#pragma unroll
    for (int j = 0; j < 4; ++j) acc[i][j] = (f32x4)0.f;

  const int sm = tid >> 1, skb = (tid & 1) * 32;  // staging row + 32-short k-chunk
  const int fr = lane & 15, kc = (lane >> 4) * 8;
  const int lr = (lane >> 4) * 4, lc = lane & 15;

  // ---- phase 1: GEMM1 over K=512, BK=64 ----
  for (int k0 = 0; k0 < 512; k0 += 64) {
    {
      const unsigned short* ap = &zb[(size_t)(bm + sm) * 512 + k0 + skb];
#pragma unroll
      for (int j = 0; j < 4; ++j)
        *reinterpret_cast<ushort8*>(&As[sm][skb + j * 8]) =
            *reinterpret_cast<const ushort8*>(ap + j * 8);
    }
    {
      const unsigned short* bp = &W1t[(size_t)(bn + sm) * 512 + k0 + skb];
#pragma unroll
      for (int j = 0; j < 4; ++j)
        *reinterpret_cast<ushort8*>(&Bs[sm][skb + j * 8]) =
            *reinterpret_cast<const ushort8*>(bp + j * 8);
    }
    __syncthreads();
#pragma unroll
    for (int s = 0; s < 2; ++s) {
      short8 af[4], bfv[4];
#pragma unroll
      for (int f = 0; f < 4; ++f)
        af[f] = *reinterpret_cast<const short8*>(&As[wm * 64 + f * 16 + fr][s * 32 + kc]);
#pragma unroll
      for (int f = 0; f < 4; ++f)
        bfv[f] = *reinterpret_cast<const short8*>(&Bs[wn * 64 + f * 16 + fr][s * 32 + kc]);
#pragma unroll
      for (int fm = 0; fm < 4; ++fm)
#pragma unroll
        for (int fn = 0; fn < 4; ++fn)
          acc[fm][fn] = __builtin_amdgcn_mfma_f32_16x16x32_bf16(af[fm], bfv[fn], acc[fm][fn], 0, 0, 0);
    }
    __syncthreads();
  }

  // ---- epilogue: h_tile = relu(acc + b1) bf16 -> LDS H2 ----
#pragma unroll
  for (int fn = 0; fn < 4; ++fn) {
    const int col_l = wn * 64 + fn * 16 + lc;
    const float bv = b1[bn + col_l];
#pragma unroll
    for (int fm = 0; fm < 4; ++fm) {
      const int row_l0 = wm * 64 + fm * 16 + lr;
#pragma unroll
      for (int r = 0; r < 4; ++r)
        H2[row_l0 + r][col_l] = f2bf(fmaxf(acc[fm][fn][r] + bv, 0.f));
    }
  }
  __syncthreads();

  // copy H2 -> global h (coalesced)
  {
    const int row = tid >> 1, c0 = (tid & 1) * 64;
    unsigned short* hp = &h[(size_t)(bm + row) * 1024 + bn + c0];
#pragma unroll
    for (int j = 0; j < 8; ++j)
      *reinterpret_cast<ushort8*>(hp + j * 8) = *reinterpret_cast<const ushort8*>(&H2[row][c0 + j * 8]);
  }

  // ---- phase 2: GEMM2 slice ----
  f32x4 acc2[4][4];
#pragma unroll
  for (int i = 0; i < 4; ++i)
#pragma unroll
    for (int j = 0; j < 4; ++j) acc2[i][j] = (f32x4)0.f;

#pragma unroll
  for (int ks = 0; ks < 4; ++ks) {
    short8 af2[4], bf2v[4];
#pragma unroll
    for (int fm = 0; fm < 4; ++fm)
      af2[fm] = *reinterpret_cast<const short8*>(&H2[wm * 64 + fm * 16 + fr][ks * 32 + kc]);
#pragma unroll
    for (int fn = 0; fn < 4; ++fn)
      bf2v[fn] = *reinterpret_cast<const short8*>(
          &WRt[(size_t)(wn * 64 + fn * 16 + fr) * 1024 + bn + ks * 32 + kc]);
#pragma unroll
    for (int fm = 0; fm < 4; ++fm)
#pragma unroll
      for (int fn = 0; fn < 4; ++fn)
        acc2[fm][fn] = __builtin_amdgcn_mfma_f32_16x16x32_bf16(af2[fm], bf2v[fn], acc2[fm][fn], 0, 0, 0);
  }

  float* pp = part + (size_t)bx * B * 128;
#pragma unroll
  for (int fn = 0; fn < 4; ++fn) {
    const int col = wn * 64 + fn * 16 + lc;
#pragma unroll
    for (int fm = 0; fm < 4; ++fm) {
      const int row0 = bm + wm * 64 + fm * 16 + lr;
#pragma unroll
      for (int r = 0; r < 4; ++r)
        pp[(size_t)(row0 + r) * 128 + col] = acc2[fm][fn][r];
    }
  }
}

// ---------------- threshold = sigmoid(h @ Wt + bt), h bf16 ----------------
__global__ __launch_bounds__(256) void thresh_kernel(const unsigned short* __restrict__ h,
                                                     const float* __restrict__ Wt,
                                                     const float* __restrict__ bt,
                                                     float* __restrict__ out, int B) {
  const int lane = threadIdx.x & 63;
  const int row = blockIdx.x * 4 + (threadIdx.x >> 6);
  if (row >= B) return;
  const unsigned short* hr = h + (size_t)row * 1024;
  float s = 0.f;
#pragma unroll
  for (int it = 0; it < 2; ++it) {
    const int k = (lane + it * 64) * 8;
    const ushort8 a = *reinterpret_cast<const ushort8*>(&hr[k]);
    const float4 w0 = *reinterpret_cast<const float4*>(&Wt[k]);
    const float4 w1 = *reinterpret_cast<const float4*>(&Wt[k + 4]);
    s += bf2f(a[0]) * w0.x + bf2f(a[1]) * w0.y + bf2f(a[2]) * w0.z + bf2f(a[3]) * w0.w;
    s += bf2f(a[4]) * w1.x + bf2f(a[5]) * w1.y + bf2f(a[6]) * w1.z + bf2f(a[7]) * w1.w;
  }
#pragma unroll
  for (int off = 32; off; off >>= 1) s += __shfl_xor(s, off);
  if (lane == 0) out[row] = 1.f / (1.f + expf(-(s + bt[0])));
}

// ---------------- fused partial-reduce + sigmoid + per-(b,g) soft-VM scan ----------------
__global__ __launch_bounds__(256) void scan2_kernel(const float* __restrict__ part,
                                                    const float* __restrict__ bR,
                                                    const float* __restrict__ prog,
                                                    const float* __restrict__ plen,
                                                    float* __restrict__ Rfinal, int B) {
  __shared__ float s_bits[16][128];
  __shared__ float s_prog[16][80];
  __shared__ float s_plen[16];
  const int tid = threadIdx.x;
  const int b0 = blockIdx.x * 16;
  // sum 8 K-split slices (ascending, same order as old reduce_sig) + bias -> sigmoid -> LDS
#pragma unroll
  for (int j = 0; j < 8; ++j) {
    const int f = tid + 256 * j;   // 0..2047
    const int lb = f >> 7, c = f & 127;
    float s = part[(size_t)(b0 + lb) * 128 + c];
#pragma unroll
    for (int sl = 1; sl < 8; ++sl)
      s += part[(size_t)sl * B * 128 + (size_t)(b0 + lb) * 128 + c];
    s_bits[lb][c] = 1.f / (1.f + expf(-(s + bR[c])));
  }
#pragma unroll
  for (int j = 0; j < 5; ++j) {
    const int f = tid + 256 * j;
    s_prog[f / 80][f % 80] = prog[(size_t)b0 * 80 + f];
  }
  if (tid < 16) s_plen[tid] = plen[b0 + tid];
  __syncthreads();

  const int lb = tid >> 4, g = tid & 15;
  const int bg = (b0 + lb) * 16 + g;

  uint32_t k2a, k2b;
  { uint32_t x0 = 0u, x1 = 1u; threefry2x32(0u, 42u, x0, x1); k2a = x0; k2b = x1; }
  uint32_t p0, p1;
  {
    uint32_t x0 = 0u, x1 = (uint32_t)bg * 2u;
    threefry2x32(k2a, k2b, x0, x1);
    p0 = (x0 ^ x1) & 127u;
  }
  {
    uint32_t x0 = 0u, x1 = (uint32_t)bg * 2u + 1u;
    threefry2x32(k2a, k2b, x0, x1);
    p1 = (x0 ^ x1) & 127u;
  }

  float R[8], M[8];
#pragma unroll
  for (int r = 0; r < 8; ++r) {
    float a = 0.f;
#pragma unroll
    for (int bit = 0; bit < 16; ++bit) {
      const int pos = r * 16 + bit;
      float v = s_bits[lb][pos];
      const bool flip = (g != 0) && ((int)p0 == pos || (int)p1 == pos);
      v = flip ? 1.0f - v : v;
      a = fmaf(v, (float)(1 << bit), a);
    }
    R[r] = a;
    M[r] = 0.f;
  }

  const float pl = s_plen[lb];
  for (int t = 0; t < 16; ++t) {
    const float op = s_prog[lb][t * 5 + 0];
    const float dst = s_prog[lb][t * 5 + 1];
    const float sa = s_prog[lb][t * 5 + 2];
    const float sb = s_prog[lb][t * 5 + 3];
    const float imm = s_prog[lb][t * 5 + 4];
    const float active = fminf(fmaxf(pl - (float)t, 0.f), 1.f);
    float r1 = 0.f, r2 = 0.f, m1 = 0.f, old = 0.f;
    float wd[8];
#pragma unroll
    for (int i = 0; i < 8; ++i) {
      const float w1 = fmaxf(1.f - fabsf(sa - (float)i), 0.f);
      const float w2 = fmaxf(1.f - fabsf(sb - (float)i), 0.f);
      wd[i] = fmaxf(1.f - fabsf(dst - (float)i), 0.f);
      r1 = fmaf(w1, R[i], r1);
      r2 = fmaf(w2, R[i], r2);
      m1 = fmaf(w1, M[i], m1);
      old = fmaf(wd[i], R[i], old);
    }
    float results[16];
    results[0] = old;               results[1] = r1 + r2;
    results[2] = r1 - r2;           results[3] = r1 * r2 * (1.f / 65536.f);
    results[4] = r1;                results[5] = imm;
    results[6] = r1 + imm;          results[7] = fmaxf(r1, r2);
    results[8] = fminf(r1, r2);     results[9] = -r1;
    results[10] = 0.5f * r1;        results[11] = r2;
    results[12] = m1;               results[13] = old;
    results[14] = fabsf(r1);        results[15] = old;
    float res = 0.f;
    const float pstore = fmaxf(1.f - fabsf(op - 13.f), 0.f);
#pragma unroll
    for (int o = 0; o < 16; ++o) res = fmaf(fmaxf(1.f - fabsf(op - (float)o), 0.f), results[o], res);
#pragma unroll
    for (int i = 0; i < 8; ++i) {
      R[i] = fmaf(active * wd[i], res - R[i], R[i]);
      M[i] = fmaf(active * pstore * wd[i], r1 - M[i], M[i]);
    }
  }

  float* outp = Rfinal + (size_t)bg * 8;
#pragma unroll
  for (int r = 0; r < 8; ++r) outp[r] = R[r];
}

// ---------------- expand: W fragment in registers, each wave loops 32 rows ----------------
__global__ __launch_bounds__(256) void final_expand2(const float* __restrict__ Rf,
                                                     const float* __restrict__ W,
                                                     const float* __restrict__ bias,
                                                     const float* __restrict__ gam,
                                                     const float* __restrict__ bet,
                                                     float* __restrict__ out, int rowsPerWave) {
  const int lane = threadIdx.x & 63;
  const int w = blockIdx.x * 4 + (threadIdx.x >> 6);
  const int h0 = lane * 8;

  float wreg[8][8];
#pragma unroll
  for (int reg = 0; reg < 8; ++reg) {
    const float4 wa = *reinterpret_cast<const float4*>(&W[reg * 512 + h0]);
    const float4 wb = *reinterpret_cast<const float4*>(&W[reg * 512 + h0 + 4]);
    wreg[reg][0] = wa.x; wreg[reg][1] = wa.y; wreg[reg][2] = wa.z; wreg[reg][3] = wa.w;
    wreg[reg][4] = wb.x; wreg[reg][5] = wb.y; wreg[reg][6] = wb.z; wreg[reg][7] = wb.w;
  }
  float bi[8], ga[8], be[8];
  {
    const float4 a = *reinterpret_cast<const float4*>(&bias[h0]);
    const float4 b = *reinterpret_cast<const float4*>(&bias[h0 + 4]);
    bi[0] = a.x; bi[1] = a.y; bi[2] = a.z; bi[3] = a.w; bi[4] = b.x; bi[5] = b.y; bi[6] = b.z; bi[7] = b.w;
    const float4 c = *reinterpret_cast<const float4*>(&gam[h0]);
    const float4 d = *reinterpret_cast<const float4*>(&gam[h0 + 4]);
    ga[0] = c.x; ga[1] = c.y; ga[2] = c.z; ga[3] = c.w; ga[4] = d.x; ga[5] = d.y; ga[6] = d.z; ga[7] = d.w;
    const float4 e = *reinterpret_cast<const float4*>(&bet[h0]);
    const float4 f = *reinterpret_cast<const float4*>(&bet[h0 + 4]);
    be[0] = e.x; be[1] = e.y; be[2] = e.z; be[3] = e.w; be[4] = f.x; be[5] = f.y; be[6] = f.z; be[7] = f.w;
  }

  const int r0 = w * rowsPerWave;
  for (int i = 0; i < rowsPerWave; ++i) {
    const int row = r0 + i;
    const float4 ra = *reinterpret_cast<const float4*>(&Rf[(size_t)row * 8]);
    const float4 rb = *reinterpret_cast<const float4*>(&Rf[(size_t)row * 8 + 4]);
    const float r[8] = {ra.x, ra.y, ra.z, ra.w, rb.x, rb.y, rb.z, rb.w};
    float x[8];
#pragma unroll
    for (int j = 0; j < 8; ++j) x[j] = bi[j];
#pragma unroll
    for (int reg = 0; reg < 8; ++reg)
#pragma unroll
      for (int j = 0; j < 8; ++j) x[j] = fmaf(r[reg], wreg[reg][j], x[j]);
    float s1 = 0.f, s2 = 0.f;
#pragma unroll
    for (int j = 0; j < 8; ++j) { s1 += x[j]; s2 = fmaf(x[j], x[j], s2); }
#pragma unroll
    for (int off = 32; off; off >>= 1) { s1 += __shfl_xor(s1, off); s2 += __shfl_xor(s2, off); }
    const float mean = s1 * (1.f / 512.f);
    const float var = s2 * (1.f / 512.f) - mean * mean;
    const float inv = rsqrtf(var + 1e-5f);
    float y[8];
#pragma unroll
    for (int j = 0; j < 8; ++j) y[j] = (x[j] - mean) * inv * ga[j] + be[j];
    float* dst = out + (size_t)row * 512 + h0;
    *reinterpret_cast<float4*>(dst) = make_float4(y[0], y[1], y[2], y[3]);
    *reinterpret_cast<float4*>(dst + 4) = make_float4(y[4], y[5], y[6], y[7]);
  }
}

// ---------------- launch ----------------
extern "C" void kernel_launch(void* const* d_in, const int* in_sizes, int n_in,
                              void* d_out, int out_size, void* d_ws, size_t ws_size,
                              hipStream_t stream) {
  const float* z    = (const float*)d_in[0];
  const float* P_op = (const float*)d_in[1];
  const float* P_dst= (const float*)d_in[2];
  const float* P_s1 = (const float*)d_in[3];
  const float* P_s2 = (const float*)d_in[4];
  const float* P_imm= (const float*)d_in[5];
  const float* Plen = (const float*)d_in[6];
  const float* W1   = (const float*)d_in[8];
  const float* b1   = (const float*)d_in[9];
  const float* WR   = (const float*)d_in[10];
  const float* bR   = (const float*)d_in[11];
  const float* Wt   = (const float*)d_in[12];
  const float* bt   = (const float*)d_in[13];
  const float* W_r2h= (const float*)d_in[14];
  const float* b_r2h= (const float*)d_in[15];
  const float* ln_g = (const float*)d_in[16];
  const float* ln_b = (const float*)d_in[17];

  const int B = in_sizes[0] / 512;  // 8192
  float* out = (float*)d_out;
  unsigned short* h = (unsigned short*)out;            // B*1024 bf16, consumed before final_expand2
  float* part    = out + (size_t)(1 << 25);            // 8 * B*128 f32 K-split partials
  float* thr_out = out + (size_t)B * 16 * 512;         // threshold output region

  float* ws = (float*)d_ws;
  float* prog   = ws;                                  // B*16*5
  float* plen   = prog + (size_t)B * 80;               // B
  float* Rfinal = plen + B;                            // B*16*8
  unsigned short* W1t = (unsigned short*)(Rfinal + (size_t)B * 128);  // 1024x512 bf16
  unsigned short* WRt = W1t + (size_t)1024 * 512;                     // 128x1024 bf16
  unsigned short* zb  = WRt + (size_t)128 * 1024;                     // B*512 bf16

  const dim3 blk(256);
  prep_kernel<<<dim3(3200), blk, 0, stream>>>(z, zb, B * 512 / 8, W1, WR, W1t, WRt,
                                              P_op, P_dst, P_s1, P_s2, P_imm, Plen,
                                              prog, plen, B * 16);
  gemm_fused<<<dim3(8, B / 128), blk, 0, stream>>>(zb, W1t, b1, WRt, h, part, B);
  thresh_kernel<<<dim3(B / 4), blk, 0, stream>>>(h, Wt, bt, thr_out, B);
  scan2_kernel<<<dim3(B / 16), blk, 0, stream>>>(part, bR, prog, plen, Rfinal, B);
  final_expand2<<<dim3(B * 16 / 4 / 32), blk, 0, stream>>>(Rfinal, W_r2h, b_r2h, ln_g, ln_b, out,
                                                           32);
}

// Round 8
// 114.349 us; speedup vs baseline: 2.7317x; 1.0576x over previous
//
#include <hip/hip_runtime.h>
#include <stdint.h>

typedef __attribute__((ext_vector_type(8))) short short8;
typedef __attribute__((ext_vector_type(4))) float f32x4;
typedef __attribute__((ext_vector_type(8))) unsigned short ushort8;
typedef __attribute__((ext_vector_type(4))) unsigned short ushort4v;

__device__ __forceinline__ unsigned short f2bf(float f) {
  uint32_t u = __float_as_uint(f);
  uint32_t r = (u + 0x7fffu + ((u >> 16) & 1u)) >> 16;  // RNE
  return (unsigned short)r;
}
__device__ __forceinline__ float bf2f(unsigned short v) {
  return __uint_as_float(((uint32_t)v) << 16);
}

// ---------------- Threefry-2x32-20 (exact JAX partitionable semantics) ----------------
__device__ __forceinline__ uint32_t rotl32(uint32_t v, int d) { return (v << d) | (v >> (32 - d)); }

__device__ __forceinline__ void threefry2x32(uint32_t k0, uint32_t k1, uint32_t& x0, uint32_t& x1) {
  const uint32_t ks2 = k0 ^ k1 ^ 0x1BD11BDAu;
  x0 += k0; x1 += k1;
  x0 += x1; x1 = rotl32(x1, 13); x1 ^= x0;
  x0 += x1; x1 = rotl32(x1, 15); x1 ^= x0;
  x0 += x1; x1 = rotl32(x1, 26); x1 ^= x0;
  x0 += x1; x1 = rotl32(x1, 6);  x1 ^= x0;
  x0 += k1; x1 += ks2 + 1u;
  x0 += x1; x1 = rotl32(x1, 17); x1 ^= x0;
  x0 += x1; x1 = rotl32(x1, 29); x1 ^= x0;
  x0 += x1; x1 = rotl32(x1, 16); x1 ^= x0;
  x0 += x1; x1 = rotl32(x1, 24); x1 ^= x0;
  x0 += ks2; x1 += k0 + 2u;
  x0 += x1; x1 = rotl32(x1, 13); x1 ^= x0;
  x0 += x1; x1 = rotl32(x1, 15); x1 ^= x0;
  x0 += x1; x1 = rotl32(x1, 26); x1 ^= x0;
  x0 += x1; x1 = rotl32(x1, 6);  x1 ^= x0;
  x0 += k0; x1 += k1 + 3u;
  x0 += x1; x1 = rotl32(x1, 17); x1 ^= x0;
  x0 += x1; x1 = rotl32(x1, 29); x1 ^= x0;
  x0 += x1; x1 = rotl32(x1, 16); x1 ^= x0;
  x0 += x1; x1 = rotl32(x1, 24); x1 ^= x0;
  x0 += k1; x1 += ks2 + 4u;
  x0 += x1; x1 = rotl32(x1, 13); x1 ^= x0;
  x0 += x1; x1 = rotl32(x1, 15); x1 ^= x0;
  x0 += x1; x1 = rotl32(x1, 26); x1 ^= x0;
  x0 += x1; x1 = rotl32(x1, 6);  x1 ^= x0;
  x0 += ks2; x1 += k0 + 5u;
}

// ---------------- prep: cast z->bf16 | transpose+cast W1,WR | decode prog ----------------
__global__ __launch_bounds__(256) void prep_kernel(const float* __restrict__ z,
                                                   unsigned short* __restrict__ zb, int n8,
                                                   const float* __restrict__ W1,
                                                   const float* __restrict__ WR,
                                                   unsigned short* __restrict__ W1t,
                                                   unsigned short* __restrict__ WRt,
                                                   const float* __restrict__ P_op,
                                                   const float* __restrict__ P_dst,
                                                   const float* __restrict__ P_s1,
                                                   const float* __restrict__ P_s2,
                                                   const float* __restrict__ P_imm,
                                                   const float* __restrict__ Plen,
                                                   float* __restrict__ prog,
                                                   float* __restrict__ plen, int BT) {
  __shared__ float t[32][33];
  const int tid = threadIdx.x;
  const int bx = blockIdx.x;
  if (bx < 2048) {                       // ---- cast z -> bf16 ----
    const int i = bx * 256 + tid;
    if (i >= n8) return;
    const float4 a = reinterpret_cast<const float4*>(z)[i * 2];
    const float4 b = reinterpret_cast<const float4*>(z)[i * 2 + 1];
    ushort8 u;
    u[0] = f2bf(a.x); u[1] = f2bf(a.y); u[2] = f2bf(a.z); u[3] = f2bf(a.w);
    u[4] = f2bf(b.x); u[5] = f2bf(b.y); u[6] = f2bf(b.z); u[7] = f2bf(b.w);
    reinterpret_cast<ushort8*>(zb)[i] = u;
  } else if (bx < 2688) {                // ---- transpose + cast weights ----
    const int b = bx - 2048;
    const float* src; unsigned short* dst; int N, K, k0, n0;
    if (b < 512) {
      src = W1; dst = W1t; N = 1024; K = 512;
      k0 = (b & 15) * 32; n0 = (b >> 4) * 32;
    } else {
      const int b2 = b - 512;
      src = WR; dst = WRt; N = 128; K = 1024;
      k0 = (b2 & 31) * 32; n0 = (b2 >> 5) * 32;
    }
    {
      const int row = tid >> 3, c4 = (tid & 7) * 4;
      const float4 v = *reinterpret_cast<const float4*>(&src[(size_t)(k0 + row) * N + n0 + c4]);
      t[row][c4] = v.x; t[row][c4 + 1] = v.y; t[row][c4 + 2] = v.z; t[row][c4 + 3] = v.w;
    }
    __syncthreads();
    {
      const int n = tid >> 3, k4 = (tid & 7) * 4;
      ushort4v o;
      o.x = f2bf(t[k4 + 0][n]); o.y = f2bf(t[k4 + 1][n]);
      o.z = f2bf(t[k4 + 2][n]); o.w = f2bf(t[k4 + 3][n]);
      *reinterpret_cast<ushort4v*>(&dst[(size_t)(n0 + n) * K + k0 + k4]) = o;
    }
  } else {                               // ---- decode prog ----
    const int i = (bx - 2688) * 256 + tid;
    if (i >= BT) return;
    const float* po = P_op + (size_t)i * 4;
    const float op = po[0] + 2.f * po[1] + 4.f * po[2] + 8.f * po[3];
    const float* pd = P_dst + (size_t)i * 3;
    const float dv = pd[0] + 2.f * pd[1] + 4.f * pd[2];
    const float* p1 = P_s1 + (size_t)i * 3;
    const float s1v = p1[0] + 2.f * p1[1] + 4.f * p1[2];
    const float* p2 = P_s2 + (size_t)i * 3;
    const float s2v = p2[0] + 2.f * p2[1] + 4.f * p2[2];
    const float* pi = P_imm + (size_t)i * 3;
    const float imv = pi[0] + 2.f * pi[1] + 4.f * pi[2];
    float* o = prog + (size_t)i * 5;
    o[0] = op; o[1] = dv; o[2] = s1v; o[3] = s2v; o[4] = imv;
    if ((i & 15) == 0) {
      const int b = i >> 4;
      const float* pl = Plen + (size_t)b * 4;
      plen[b] = pl[0] + 2.f * pl[1] + 4.f * pl[2] + 8.f * pl[3];
    }
  }
}

// ---------------- fused GEMM1 + GEMM2-slice + threshold-slice, BK=64; h never hits global ----------------
__global__ __launch_bounds__(256) void gemm_fused(const unsigned short* __restrict__ zb,
                                                  const unsigned short* __restrict__ W1t,
                                                  const float* __restrict__ b1,
                                                  const unsigned short* __restrict__ WRt,
                                                  const float* __restrict__ Wt,
                                                  float* __restrict__ part,
                                                  float* __restrict__ thr_part, int B) {
  __shared__ __align__(16) char smem[36864];
  auto As = reinterpret_cast<unsigned short (*)[72]>(smem);           // phase 1: [128][72]
  auto Bs = reinterpret_cast<unsigned short (*)[72]>(smem + 18432);   // phase 1: [128][72]
  auto H2 = reinterpret_cast<unsigned short (*)[136]>(smem);          // phase 2/3: [128][136]

  const int tid = threadIdx.x;
  const int lane = tid & 63, wave = tid >> 6;
  const int wm = wave >> 1, wn = wave & 1;
  const int bx = blockIdx.x, bm = blockIdx.y * 128, bn = bx * 128;

  f32x4 acc[4][4];
#pragma unroll
  for (int i = 0; i < 4; ++i)
#pragma unroll
    for (int j = 0; j < 4; ++j) acc[i][j] = (f32x4)0.f;

  const int sm = tid >> 1, skb = (tid & 1) * 32;
  const int fr = lane & 15, kc = (lane >> 4) * 8;
  const int lr = (lane >> 4) * 4, lc = lane & 15;

  // ---- phase 1: GEMM1 over K=512, BK=64 ----
  for (int k0 = 0; k0 < 512; k0 += 64) {
    {
      const unsigned short* ap = &zb[(size_t)(bm + sm) * 512 + k0 + skb];
#pragma unroll
      for (int j = 0; j < 4; ++j)
        *reinterpret_cast<ushort8*>(&As[sm][skb + j * 8]) =
            *reinterpret_cast<const ushort8*>(ap + j * 8);
    }
    {
      const unsigned short* bp = &W1t[(size_t)(bn + sm) * 512 + k0 + skb];
#pragma unroll
      for (int j = 0; j < 4; ++j)
        *reinterpret_cast<ushort8*>(&Bs[sm][skb + j * 8]) =
            *reinterpret_cast<const ushort8*>(bp + j * 8);
    }
    __syncthreads();
#pragma unroll
    for (int s = 0; s < 2; ++s) {
      short8 af[4], bfv[4];
#pragma unroll
      for (int f = 0; f < 4; ++f)
        af[f] = *reinterpret_cast<const short8*>(&As[wm * 64 + f * 16 + fr][s * 32 + kc]);
#pragma unroll
      for (int f = 0; f < 4; ++f)
        bfv[f] = *reinterpret_cast<const short8*>(&Bs[wn * 64 + f * 16 + fr][s * 32 + kc]);
#pragma unroll
      for (int fm = 0; fm < 4; ++fm)
#pragma unroll
        for (int fn = 0; fn < 4; ++fn)
          acc[fm][fn] = __builtin_amdgcn_mfma_f32_16x16x32_bf16(af[fm], bfv[fn], acc[fm][fn], 0, 0, 0);
    }
    __syncthreads();
  }

  // ---- epilogue: h_tile = relu(acc + b1) bf16 -> LDS H2 ----
#pragma unroll
  for (int fn = 0; fn < 4; ++fn) {
    const int col_l = wn * 64 + fn * 16 + lc;
    const float bv = b1[bn + col_l];
#pragma unroll
    for (int fm = 0; fm < 4; ++fm) {
      const int row_l0 = wm * 64 + fm * 16 + lr;
#pragma unroll
      for (int r = 0; r < 4; ++r)
        H2[row_l0 + r][col_l] = f2bf(fmaxf(acc[fm][fn][r] + bv, 0.f));
    }
  }
  __syncthreads();

  // ---- phase 3: threshold partial: thr_part[bx][bm+row] = sum_k h_tile[row][k] * Wt[bn+k] ----
  {
    const int row = tid >> 1, half = tid & 1;
    const unsigned short* hp = &H2[row][half * 64];
    const float* wp = &Wt[bn + half * 64];
    float s = 0.f;
#pragma unroll
    for (int j = 0; j < 8; ++j) {
      const ushort8 a = *reinterpret_cast<const ushort8*>(hp + j * 8);
      const float4 w0 = *reinterpret_cast<const float4*>(wp + j * 8);
      const float4 w1 = *reinterpret_cast<const float4*>(wp + j * 8 + 4);
      s += bf2f(a[0]) * w0.x + bf2f(a[1]) * w0.y + bf2f(a[2]) * w0.z + bf2f(a[3]) * w0.w;
      s += bf2f(a[4]) * w1.x + bf2f(a[5]) * w1.y + bf2f(a[6]) * w1.z + bf2f(a[7]) * w1.w;
    }
    s += __shfl_xor(s, 1);
    if (half == 0) thr_part[(size_t)bx * B + bm + row] = s;
  }

  // ---- phase 2: GEMM2 slice ----
  f32x4 acc2[4][4];
#pragma unroll
  for (int i = 0; i < 4; ++i)
#pragma unroll
    for (int j = 0; j < 4; ++j) acc2[i][j] = (f32x4)0.f;

#pragma unroll
  for (int ks = 0; ks < 4; ++ks) {
    short8 af2[4], bf2v[4];
#pragma unroll
    for (int fm = 0; fm < 4; ++fm)
      af2[fm] = *reinterpret_cast<const short8*>(&H2[wm * 64 + fm * 16 + fr][ks * 32 + kc]);
#pragma unroll
    for (int fn = 0; fn < 4; ++fn)
      bf2v[fn] = *reinterpret_cast<const short8*>(
          &WRt[(size_t)(wn * 64 + fn * 16 + fr) * 1024 + bn + ks * 32 + kc]);
#pragma unroll
    for (int fm = 0; fm < 4; ++fm)
#pragma unroll
      for (int fn = 0; fn < 4; ++fn)
        acc2[fm][fn] = __builtin_amdgcn_mfma_f32_16x16x32_bf16(af2[fm], bf2v[fn], acc2[fm][fn], 0, 0, 0);
  }

  float* pp = part + (size_t)bx * B * 128;
#pragma unroll
  for (int fn = 0; fn < 4; ++fn) {
    const int col = wn * 64 + fn * 16 + lc;
#pragma unroll
    for (int fm = 0; fm < 4; ++fm) {
      const int row0 = bm + wm * 64 + fm * 16 + lr;
#pragma unroll
      for (int r = 0; r < 4; ++r)
        pp[(size_t)(row0 + r) * 128 + col] = acc2[fm][fn][r];
    }
  }
}

// ---------------- fused partial-reduce + sigmoid + soft-VM scan + threshold finish ----------------
__global__ __launch_bounds__(256) void scan2_kernel(const float* __restrict__ part,
                                                    const float* __restrict__ bR,
                                                    const float* __restrict__ thr_part,
                                                    const float* __restrict__ bt,
                                                    const float* __restrict__ prog,
                                                    const float* __restrict__ plen,
                                                    float* __restrict__ Rfinal,
                                                    float* __restrict__ thr_out, int B) {
  __shared__ float s_bits[16][128];
  __shared__ float s_prog[16][80];
  __shared__ float s_plen[16];
  const int tid = threadIdx.x;
  const int b0 = blockIdx.x * 16;
#pragma unroll
  for (int j = 0; j < 8; ++j) {
    const int f = tid + 256 * j;   // 0..2047
    const int lb = f >> 7, c = f & 127;
    float s = part[(size_t)(b0 + lb) * 128 + c];
#pragma unroll
    for (int sl = 1; sl < 8; ++sl)
      s += part[(size_t)sl * B * 128 + (size_t)(b0 + lb) * 128 + c];
    s_bits[lb][c] = 1.f / (1.f + expf(-(s + bR[c])));
  }
#pragma unroll
  for (int j = 0; j < 5; ++j) {
    const int f = tid + 256 * j;
    s_prog[f / 80][f % 80] = prog[(size_t)b0 * 80 + f];
  }
  if (tid < 16) {
    s_plen[tid] = plen[b0 + tid];
    float s = thr_part[b0 + tid];
#pragma unroll
    for (int sl = 1; sl < 8; ++sl) s += thr_part[(size_t)sl * B + b0 + tid];
    thr_out[b0 + tid] = 1.f / (1.f + expf(-(s + bt[0])));
  }
  __syncthreads();

  const int lb = tid >> 4, g = tid & 15;
  const int bg = (b0 + lb) * 16 + g;

  uint32_t k2a, k2b;
  { uint32_t x0 = 0u, x1 = 1u; threefry2x32(0u, 42u, x0, x1); k2a = x0; k2b = x1; }
  uint32_t p0, p1;
  {
    uint32_t x0 = 0u, x1 = (uint32_t)bg * 2u;
    threefry2x32(k2a, k2b, x0, x1);
    p0 = (x0 ^ x1) & 127u;
  }
  {
    uint32_t x0 = 0u, x1 = (uint32_t)bg * 2u + 1u;
    threefry2x32(k2a, k2b, x0, x1);
    p1 = (x0 ^ x1) & 127u;
  }

  float R[8], M[8];
#pragma unroll
  for (int r = 0; r < 8; ++r) {
    float a = 0.f;
#pragma unroll
    for (int bit = 0; bit < 16; ++bit) {
      const int pos = r * 16 + bit;
      float v = s_bits[lb][pos];
      const bool flip = (g != 0) && ((int)p0 == pos || (int)p1 == pos);
      v = flip ? 1.0f - v : v;
      a = fmaf(v, (float)(1 << bit), a);
    }
    R[r] = a;
    M[r] = 0.f;
  }

  const float pl = s_plen[lb];
  for (int t = 0; t < 16; ++t) {
    const float op = s_prog[lb][t * 5 + 0];
    const float dst = s_prog[lb][t * 5 + 1];
    const float sa = s_prog[lb][t * 5 + 2];
    const float sb = s_prog[lb][t * 5 + 3];
    const float imm = s_prog[lb][t * 5 + 4];
    const float active = fminf(fmaxf(pl - (float)t, 0.f), 1.f);
    float r1 = 0.f, r2 = 0.f, m1 = 0.f, old = 0.f;
    float wd[8];
#pragma unroll
    for (int i = 0; i < 8; ++i) {
      const float w1 = fmaxf(1.f - fabsf(sa - (float)i), 0.f);
      const float w2 = fmaxf(1.f - fabsf(sb - (float)i), 0.f);
      wd[i] = fmaxf(1.f - fabsf(dst - (float)i), 0.f);
      r1 = fmaf(w1, R[i], r1);
      r2 = fmaf(w2, R[i], r2);
      m1 = fmaf(w1, M[i], m1);
      old = fmaf(wd[i], R[i], old);
    }
    float results[16];
    results[0] = old;               results[1] = r1 + r2;
    results[2] = r1 - r2;           results[3] = r1 * r2 * (1.f / 65536.f);
    results[4] = r1;                results[5] = imm;
    results[6] = r1 + imm;          results[7] = fmaxf(r1, r2);
    results[8] = fminf(r1, r2);     results[9] = -r1;
    results[10] = 0.5f * r1;        results[11] = r2;
    results[12] = m1;               results[13] = old;
    results[14] = fabsf(r1);        results[15] = old;
    float res = 0.f;
    const float pstore = fmaxf(1.f - fabsf(op - 13.f), 0.f);
#pragma unroll
    for (int o = 0; o < 16; ++o) res = fmaf(fmaxf(1.f - fabsf(op - (float)o), 0.f), results[o], res);
#pragma unroll
    for (int i = 0; i < 8; ++i) {
      R[i] = fmaf(active * wd[i], res - R[i], R[i]);
      M[i] = fmaf(active * pstore * wd[i], r1 - M[i], M[i]);
    }
  }

  float* outp = Rfinal + (size_t)bg * 8;
#pragma unroll
  for (int r = 0; r < 8; ++r) outp[r] = R[r];
}

// ---------------- expand: W fragment in registers, each wave loops 32 rows ----------------
__global__ __launch_bounds__(256) void final_expand2(const float* __restrict__ Rf,
                                                     const float* __restrict__ W,
                                                     const float* __restrict__ bias,
                                                     const float* __restrict__ gam,
                                                     const float* __restrict__ bet,
                                                     float* __restrict__ out, int rowsPerWave) {
  const int lane = threadIdx.x & 63;
  const int w = blockIdx.x * 4 + (threadIdx.x >> 6);
  const int h0 = lane * 8;

  float wreg[8][8];
#pragma unroll
  for (int reg = 0; reg < 8; ++reg) {
    const float4 wa = *reinterpret_cast<const float4*>(&W[reg * 512 + h0]);
    const float4 wb = *reinterpret_cast<const float4*>(&W[reg * 512 + h0 + 4]);
    wreg[reg][0] = wa.x; wreg[reg][1] = wa.y; wreg[reg][2] = wa.z; wreg[reg][3] = wa.w;
    wreg[reg][4] = wb.x; wreg[reg][5] = wb.y; wreg[reg][6] = wb.z; wreg[reg][7] = wb.w;
  }
  float bi[8], ga[8], be[8];
  {
    const float4 a = *reinterpret_cast<const float4*>(&bias[h0]);
    const float4 b = *reinterpret_cast<const float4*>(&bias[h0 + 4]);
    bi[0] = a.x; bi[1] = a.y; bi[2] = a.z; bi[3] = a.w; bi[4] = b.x; bi[5] = b.y; bi[6] = b.z; bi[7] = b.w;
    const float4 c = *reinterpret_cast<const float4*>(&gam[h0]);
    const float4 d = *reinterpret_cast<const float4*>(&gam[h0 + 4]);
    ga[0] = c.x; ga[1] = c.y; ga[2] = c.z; ga[3] = c.w; ga[4] = d.x; ga[5] = d.y; ga[6] = d.z; ga[7] = d.w;
    const float4 e = *reinterpret_cast<const float4*>(&bet[h0]);
    const float4 f = *reinterpret_cast<const float4*>(&bet[h0 + 4]);
    be[0] = e.x; be[1] = e.y; be[2] = e.z; be[3] = e.w; be[4] = f.x; be[5] = f.y; be[6] = f.z; be[7] = f.w;
  }

  const int r0 = w * rowsPerWave;
  for (int i = 0; i < rowsPerWave; ++i) {
    const int row = r0 + i;
    const float4 ra = *reinterpret_cast<const float4*>(&Rf[(size_t)row * 8]);
    const float4 rb = *reinterpret_cast<const float4*>(&Rf[(size_t)row * 8 + 4]);
    const float r[8] = {ra.x, ra.y, ra.z, ra.w, rb.x, rb.y, rb.z, rb.w};
    float x[8];
#pragma unroll
    for (int j = 0; j < 8; ++j) x[j] = bi[j];
#pragma unroll
    for (int reg = 0; reg < 8; ++reg)
#pragma unroll
      for (int j = 0; j < 8; ++j) x[j] = fmaf(r[reg], wreg[reg][j], x[j]);
    float s1 = 0.f, s2 = 0.f;
#pragma unroll
    for (int j = 0; j < 8; ++j) { s1 += x[j]; s2 = fmaf(x[j], x[j], s2); }
#pragma unroll
    for (int off = 32; off; off >>= 1) { s1 += __shfl_xor(s1, off); s2 += __shfl_xor(s2, off); }
    const float mean = s1 * (1.f / 512.f);
    const float var = s2 * (1.f / 512.f) - mean * mean;
    const float inv = rsqrtf(var + 1e-5f);
    float y[8];
#pragma unroll
    for (int j = 0; j < 8; ++j) y[j] = (x[j] - mean) * inv * ga[j] + be[j];
    float* dst = out + (size_t)row * 512 + h0;
    *reinterpret_cast<float4*>(dst) = make_float4(y[0], y[1], y[2], y[3]);
    *reinterpret_cast<float4*>(dst + 4) = make_float4(y[4], y[5], y[6], y[7]);
  }
}

// ---------------- launch ----------------
extern "C" void kernel_launch(void* const* d_in, const int* in_sizes, int n_in,
                              void* d_out, int out_size, void* d_ws, size_t ws_size,
                              hipStream_t stream) {
  const float* z    = (const float*)d_in[0];
  const float* P_op = (const float*)d_in[1];
  const float* P_dst= (const float*)d_in[2];
  const float* P_s1 = (const float*)d_in[3];
  const float* P_s2 = (const float*)d_in[4];
  const float* P_imm= (const float*)d_in[5];
  const float* Plen = (const float*)d_in[6];
  const float* W1   = (const float*)d_in[8];
  const float* b1   = (const float*)d_in[9];
  const float* WR   = (const float*)d_in[10];
  const float* bR   = (const float*)d_in[11];
  const float* Wt   = (const float*)d_in[12];
  const float* bt   = (const float*)d_in[13];
  const float* W_r2h= (const float*)d_in[14];
  const float* b_r2h= (const float*)d_in[15];
  const float* ln_g = (const float*)d_in[16];
  const float* ln_b = (const float*)d_in[17];

  const int B = in_sizes[0] / 512;  // 8192
  float* out = (float*)d_out;
  float* part    = out + (size_t)(1 << 25);            // 8 * B*128 f32 K-split partials (read before expand writes)
  float* thr_out = out + (size_t)B * 16 * 512;         // threshold output region

  float* ws = (float*)d_ws;
  float* prog   = ws;                                  // B*16*5
  float* plen   = prog + (size_t)B * 80;               // B
  float* Rfinal = plen + B;                            // B*16*8
  float* thr_part = Rfinal + (size_t)B * 128;          // 8 * B
  unsigned short* W1t = (unsigned short*)(thr_part + (size_t)8 * B);  // 1024x512 bf16
  unsigned short* WRt = W1t + (size_t)1024 * 512;                     // 128x1024 bf16
  unsigned short* zb  = WRt + (size_t)128 * 1024;                     // B*512 bf16

  const dim3 blk(256);
  prep_kernel<<<dim3(3200), blk, 0, stream>>>(z, zb, B * 512 / 8, W1, WR, W1t, WRt,
                                              P_op, P_dst, P_s1, P_s2, P_imm, Plen,
                                              prog, plen, B * 16);
  gemm_fused<<<dim3(8, B / 128), blk, 0, stream>>>(zb, W1t, b1, WRt, Wt, part, thr_part, B);
  scan2_kernel<<<dim3(B / 16), blk, 0, stream>>>(part, bR, thr_part, bt, prog, plen, Rfinal,
                                                 thr_out, B);
  final_expand2<<<dim3(B * 16 / 4 / 32), blk, 0, stream>>>(Rfinal, W_r2h, b_r2h, ln_g, ln_b, out,
                                                           32);
}

// Round 9
// 112.659 us; speedup vs baseline: 2.7727x; 1.0150x over previous
//
#include <hip/hip_runtime.h>
#include <stdint.h>

typedef __attribute__((ext_vector_type(8))) short short8;
typedef __attribute__((ext_vector_type(4))) float f32x4;
typedef __attribute__((ext_vector_type(8))) unsigned short ushort8;
typedef __attribute__((ext_vector_type(4))) unsigned short ushort4v;

__device__ __forceinline__ unsigned short f2bf(float f) {
  uint32_t u = __float_as_uint(f);
  uint32_t r = (u + 0x7fffu + ((u >> 16) & 1u)) >> 16;  // RNE
  return (unsigned short)r;
}
__device__ __forceinline__ float bf2f(unsigned short v) {
  return __uint_as_float(((uint32_t)v) << 16);
}

typedef __attribute__((address_space(1))) const unsigned int g_u32;
typedef __attribute__((address_space(3))) unsigned int l_u32;
__device__ __forceinline__ void gl_lds16(const void* g, void* l) {
  // async global->LDS, 16B/lane, LDS dest = wave-uniform base + lane*16
  __builtin_amdgcn_global_load_lds((g_u32*)g, (l_u32*)l, 16, 0, 0);
}

// ---------------- Threefry-2x32-20 (exact JAX partitionable semantics) ----------------
__device__ __forceinline__ uint32_t rotl32(uint32_t v, int d) { return (v << d) | (v >> (32 - d)); }

__device__ __forceinline__ void threefry2x32(uint32_t k0, uint32_t k1, uint32_t& x0, uint32_t& x1) {
  const uint32_t ks2 = k0 ^ k1 ^ 0x1BD11BDAu;
  x0 += k0; x1 += k1;
  x0 += x1; x1 = rotl32(x1, 13); x1 ^= x0;
  x0 += x1; x1 = rotl32(x1, 15); x1 ^= x0;
  x0 += x1; x1 = rotl32(x1, 26); x1 ^= x0;
  x0 += x1; x1 = rotl32(x1, 6);  x1 ^= x0;
  x0 += k1; x1 += ks2 + 1u;
  x0 += x1; x1 = rotl32(x1, 17); x1 ^= x0;
  x0 += x1; x1 = rotl32(x1, 29); x1 ^= x0;
  x0 += x1; x1 = rotl32(x1, 16); x1 ^= x0;
  x0 += x1; x1 = rotl32(x1, 24); x1 ^= x0;
  x0 += ks2; x1 += k0 + 2u;
  x0 += x1; x1 = rotl32(x1, 13); x1 ^= x0;
  x0 += x1; x1 = rotl32(x1, 15); x1 ^= x0;
  x0 += x1; x1 = rotl32(x1, 26); x1 ^= x0;
  x0 += x1; x1 = rotl32(x1, 6);  x1 ^= x0;
  x0 += k0; x1 += k1 + 3u;
  x0 += x1; x1 = rotl32(x1, 17); x1 ^= x0;
  x0 += x1; x1 = rotl32(x1, 29); x1 ^= x0;
  x0 += x1; x1 = rotl32(x1, 16); x1 ^= x0;
  x0 += x1; x1 = rotl32(x1, 24); x1 ^= x0;
  x0 += k1; x1 += ks2 + 4u;
  x0 += x1; x1 = rotl32(x1, 13); x1 ^= x0;
  x0 += x1; x1 = rotl32(x1, 15); x1 ^= x0;
  x0 += x1; x1 = rotl32(x1, 26); x1 ^= x0;
  x0 += x1; x1 = rotl32(x1, 6);  x1 ^= x0;
  x0 += ks2; x1 += k0 + 5u;
}

// ---------------- prep: cast z->bf16 | transpose+cast W1,WR | decode prog ----------------
__global__ __launch_bounds__(256) void prep_kernel(const float* __restrict__ z,
                                                   unsigned short* __restrict__ zb, int n8,
                                                   const float* __restrict__ W1,
                                                   const float* __restrict__ WR,
                                                   unsigned short* __restrict__ W1t,
                                                   unsigned short* __restrict__ WRt,
                                                   const float* __restrict__ P_op,
                                                   const float* __restrict__ P_dst,
                                                   const float* __restrict__ P_s1,
                                                   const float* __restrict__ P_s2,
                                                   const float* __restrict__ P_imm,
                                                   const float* __restrict__ Plen,
                                                   float* __restrict__ prog,
                                                   float* __restrict__ plen, int BT) {
  __shared__ float t[32][33];
  const int tid = threadIdx.x;
  const int bx = blockIdx.x;
  if (bx < 2048) {                       // ---- cast z -> bf16 ----
    const int i = bx * 256 + tid;
    if (i >= n8) return;
    const float4 a = reinterpret_cast<const float4*>(z)[i * 2];
    const float4 b = reinterpret_cast<const float4*>(z)[i * 2 + 1];
    ushort8 u;
    u[0] = f2bf(a.x); u[1] = f2bf(a.y); u[2] = f2bf(a.z); u[3] = f2bf(a.w);
    u[4] = f2bf(b.x); u[5] = f2bf(b.y); u[6] = f2bf(b.z); u[7] = f2bf(b.w);
    reinterpret_cast<ushort8*>(zb)[i] = u;
  } else if (bx < 2688) {                // ---- transpose + cast weights ----
    const int b = bx - 2048;
    const float* src; unsigned short* dst; int N, K, k0, n0;
    if (b < 512) {
      src = W1; dst = W1t; N = 1024; K = 512;
      k0 = (b & 15) * 32; n0 = (b >> 4) * 32;
    } else {
      const int b2 = b - 512;
      src = WR; dst = WRt; N = 128; K = 1024;
      k0 = (b2 & 31) * 32; n0 = (b2 >> 5) * 32;
    }
    {
      const int row = tid >> 3, c4 = (tid & 7) * 4;
      const float4 v = *reinterpret_cast<const float4*>(&src[(size_t)(k0 + row) * N + n0 + c4]);
      t[row][c4] = v.x; t[row][c4 + 1] = v.y; t[row][c4 + 2] = v.z; t[row][c4 + 3] = v.w;
    }
    __syncthreads();
    {
      const int n = tid >> 3, k4 = (tid & 7) * 4;
      ushort4v o;
      o.x = f2bf(t[k4 + 0][n]); o.y = f2bf(t[k4 + 1][n]);
      o.z = f2bf(t[k4 + 2][n]); o.w = f2bf(t[k4 + 3][n]);
      *reinterpret_cast<ushort4v*>(&dst[(size_t)(n0 + n) * K + k0 + k4]) = o;
    }
  } else {                               // ---- decode prog ----
    const int i = (bx - 2688) * 256 + tid;
    if (i >= BT) return;
    const float* po = P_op + (size_t)i * 4;
    const float op = po[0] + 2.f * po[1] + 4.f * po[2] + 8.f * po[3];
    const float* pd = P_dst + (size_t)i * 3;
    const float dv = pd[0] + 2.f * pd[1] + 4.f * pd[2];
    const float* p1 = P_s1 + (size_t)i * 3;
    const float s1v = p1[0] + 2.f * p1[1] + 4.f * p1[2];
    const float* p2 = P_s2 + (size_t)i * 3;
    const float s2v = p2[0] + 2.f * p2[1] + 4.f * p2[2];
    const float* pi = P_imm + (size_t)i * 3;
    const float imv = pi[0] + 2.f * pi[1] + 4.f * pi[2];
    float* o = prog + (size_t)i * 5;
    o[0] = op; o[1] = dv; o[2] = s1v; o[3] = s2v; o[4] = imv;
    if ((i & 15) == 0) {
      const int b = i >> 4;
      const float* pl = Plen + (size_t)b * 4;
      plen[b] = pl[0] + 2.f * pl[1] + 4.f * pl[2] + 8.f * pl[3];
    }
  }
}

// ---------------- fused GEMM1 + GEMM2-slice + threshold-slice ----------------
// Phase-1 staging via global_load_lds into linear [128][64] LDS with 16B-chunk XOR swizzle:
// physical[row][slot] = logical[row][slot ^ (row&7)]  (source address pre-swizzled; read XORs back)
__global__ __launch_bounds__(256) void gemm_fused(const unsigned short* __restrict__ zb,
                                                  const unsigned short* __restrict__ W1t,
                                                  const float* __restrict__ b1,
                                                  const unsigned short* __restrict__ WRt,
                                                  const float* __restrict__ Wt,
                                                  float* __restrict__ part,
                                                  float* __restrict__ thr_part, int B) {
  __shared__ __align__(16) char smem[34816];
  unsigned short* AsF = (unsigned short*)smem;            // phase 1: [128][64] swizzled
  unsigned short* BsF = (unsigned short*)(smem + 16384);  // phase 1: [128][64] swizzled
  auto H2 = reinterpret_cast<unsigned short (*)[136]>(smem);  // phase 2/3: [128][136]

  const int tid = threadIdx.x;
  const int lane = tid & 63, wave = tid >> 6;
  const int wm = wave >> 1, wn = wave & 1;
  const int bx = blockIdx.x, bm = blockIdx.y * 128, bn = bx * 128;

  f32x4 acc[4][4];
#pragma unroll
  for (int i = 0; i < 4; ++i)
#pragma unroll
    for (int j = 0; j < 4; ++j) acc[i][j] = (f32x4)0.f;

  const int fr = lane & 15, kc = (lane >> 4) * 8;
  const int lr = (lane >> 4) * 4, lc = lane & 15;
  const int lrow = lane >> 3, slot = lane & 7;       // staging: 8 rows x 8 chunks per wave-instr
  const int sslot = (slot ^ lrow) << 3;              // pre-swizzled source chunk (shorts)
  const int fx = fr & 7;                             // read-side swizzle key
  const int cbase = lane >> 4;                       // kc>>3

  // ---- phase 1: GEMM1 over K=512, BK=64, async staging ----
  for (int k0 = 0; k0 < 512; k0 += 64) {
#pragma unroll
    for (int i = 0; i < 4; ++i) {
      const int r0 = wave * 32 + i * 8;
      gl_lds16(&zb[(size_t)(bm + r0 + lrow) * 512 + k0 + sslot], &AsF[r0 * 64]);
    }
#pragma unroll
    for (int i = 0; i < 4; ++i) {
      const int r0 = wave * 32 + i * 8;
      gl_lds16(&W1t[(size_t)(bn + r0 + lrow) * 512 + k0 + sslot], &BsF[r0 * 64]);
    }
    __syncthreads();
#pragma unroll
    for (int s = 0; s < 2; ++s) {
      short8 af[4], bfv[4];
#pragma unroll
      for (int f = 0; f < 4; ++f) {
        const int row = wm * 64 + f * 16 + fr;
        const int c = s * 4 + cbase;
        af[f] = *reinterpret_cast<const short8*>(&AsF[row * 64 + ((c ^ fx) << 3)]);
      }
#pragma unroll
      for (int f = 0; f < 4; ++f) {
        const int row = wn * 64 + f * 16 + fr;
        const int c = s * 4 + cbase;
        bfv[f] = *reinterpret_cast<const short8*>(&BsF[row * 64 + ((c ^ fx) << 3)]);
      }
#pragma unroll
      for (int fm = 0; fm < 4; ++fm)
#pragma unroll
        for (int fn = 0; fn < 4; ++fn)
          acc[fm][fn] = __builtin_amdgcn_mfma_f32_16x16x32_bf16(af[fm], bfv[fn], acc[fm][fn], 0, 0, 0);
    }
    __syncthreads();
  }

  // ---- epilogue: h_tile = relu(acc + b1) bf16 -> LDS H2 ----
#pragma unroll
  for (int fn = 0; fn < 4; ++fn) {
    const int col_l = wn * 64 + fn * 16 + lc;
    const float bv = b1[bn + col_l];
#pragma unroll
    for (int fm = 0; fm < 4; ++fm) {
      const int row_l0 = wm * 64 + fm * 16 + lr;
#pragma unroll
      for (int r = 0; r < 4; ++r)
        H2[row_l0 + r][col_l] = f2bf(fmaxf(acc[fm][fn][r] + bv, 0.f));
    }
  }
  __syncthreads();

  // ---- phase 3: threshold partial: thr_part[bx][bm+row] = sum_k h_tile[row][k] * Wt[bn+k] ----
  {
    const int row = tid >> 1, half = tid & 1;
    const unsigned short* hp = &H2[row][half * 64];
    const float* wp = &Wt[bn + half * 64];
    float s = 0.f;
#pragma unroll
    for (int j = 0; j < 8; ++j) {
      const ushort8 a = *reinterpret_cast<const ushort8*>(hp + j * 8);
      const float4 w0 = *reinterpret_cast<const float4*>(wp + j * 8);
      const float4 w1 = *reinterpret_cast<const float4*>(wp + j * 8 + 4);
      s += bf2f(a[0]) * w0.x + bf2f(a[1]) * w0.y + bf2f(a[2]) * w0.z + bf2f(a[3]) * w0.w;
      s += bf2f(a[4]) * w1.x + bf2f(a[5]) * w1.y + bf2f(a[6]) * w1.z + bf2f(a[7]) * w1.w;
    }
    s += __shfl_xor(s, 1);
    if (half == 0) thr_part[(size_t)bx * B + bm + row] = s;
  }

  // ---- phase 2: GEMM2 slice ----
  f32x4 acc2[4][4];
#pragma unroll
  for (int i = 0; i < 4; ++i)
#pragma unroll
    for (int j = 0; j < 4; ++j) acc2[i][j] = (f32x4)0.f;

#pragma unroll
  for (int ks = 0; ks < 4; ++ks) {
    short8 af2[4], bf2v[4];
#pragma unroll
    for (int fm = 0; fm < 4; ++fm)
      af2[fm] = *reinterpret_cast<const short8*>(&H2[wm * 64 + fm * 16 + fr][ks * 32 + kc]);
#pragma unroll
    for (int fn = 0; fn < 4; ++fn)
      bf2v[fn] = *reinterpret_cast<const short8*>(
          &WRt[(size_t)(wn * 64 + fn * 16 + fr) * 1024 + bn + ks * 32 + kc]);
#pragma unroll
    for (int fm = 0; fm < 4; ++fm)
#pragma unroll
      for (int fn = 0; fn < 4; ++fn)
        acc2[fm][fn] = __builtin_amdgcn_mfma_f32_16x16x32_bf16(af2[fm], bf2v[fn], acc2[fm][fn], 0, 0, 0);
  }

  float* pp = part + (size_t)bx * B * 128;
#pragma unroll
  for (int fn = 0; fn < 4; ++fn) {
    const int col = wn * 64 + fn * 16 + lc;
#pragma unroll
    for (int fm = 0; fm < 4; ++fm) {
      const int row0 = bm + wm * 64 + fm * 16 + lr;
#pragma unroll
      for (int r = 0; r < 4; ++r)
        pp[(size_t)(row0 + r) * 128 + col] = acc2[fm][fn][r];
    }
  }
}

// ---------------- fused partial-reduce + sigmoid + soft-VM scan + threshold finish ----------------
__global__ __launch_bounds__(256) void scan2_kernel(const float* __restrict__ part,
                                                    const float* __restrict__ bR,
                                                    const float* __restrict__ thr_part,
                                                    const float* __restrict__ bt,
                                                    const float* __restrict__ prog,
                                                    const float* __restrict__ plen,
                                                    float* __restrict__ Rfinal,
                                                    float* __restrict__ thr_out, int B) {
  __shared__ float s_bits[16][128];
  __shared__ float s_prog[16][80];
  __shared__ float s_plen[16];
  const int tid = threadIdx.x;
  const int b0 = blockIdx.x * 16;
#pragma unroll
  for (int j = 0; j < 8; ++j) {
    const int f = tid + 256 * j;   // 0..2047
    const int lb = f >> 7, c = f & 127;
    float s = part[(size_t)(b0 + lb) * 128 + c];
#pragma unroll
    for (int sl = 1; sl < 8; ++sl)
      s += part[(size_t)sl * B * 128 + (size_t)(b0 + lb) * 128 + c];
    s_bits[lb][c] = 1.f / (1.f + expf(-(s + bR[c])));
  }
#pragma unroll
  for (int j = 0; j < 5; ++j) {
    const int f = tid + 256 * j;
    s_prog[f / 80][f % 80] = prog[(size_t)b0 * 80 + f];
  }
  if (tid < 16) {
    s_plen[tid] = plen[b0 + tid];
    float s = thr_part[b0 + tid];
#pragma unroll
    for (int sl = 1; sl < 8; ++sl) s += thr_part[(size_t)sl * B + b0 + tid];
    thr_out[b0 + tid] = 1.f / (1.f + expf(-(s + bt[0])));
  }
  __syncthreads();

  const int lb = tid >> 4, g = tid & 15;
  const int bg = (b0 + lb) * 16 + g;

  uint32_t k2a, k2b;
  { uint32_t x0 = 0u, x1 = 1u; threefry2x32(0u, 42u, x0, x1); k2a = x0; k2b = x1; }
  uint32_t p0, p1;
  {
    uint32_t x0 = 0u, x1 = (uint32_t)bg * 2u;
    threefry2x32(k2a, k2b, x0, x1);
    p0 = (x0 ^ x1) & 127u;
  }
  {
    uint32_t x0 = 0u, x1 = (uint32_t)bg * 2u + 1u;
    threefry2x32(k2a, k2b, x0, x1);
    p1 = (x0 ^ x1) & 127u;
  }

  float R[8], M[8];
#pragma unroll
  for (int r = 0; r < 8; ++r) {
    float a = 0.f;
#pragma unroll
    for (int bit = 0; bit < 16; ++bit) {
      const int pos = r * 16 + bit;
      float v = s_bits[lb][pos];
      const bool flip = (g != 0) && ((int)p0 == pos || (int)p1 == pos);
      v = flip ? 1.0f - v : v;
      a = fmaf(v, (float)(1 << bit), a);
    }
    R[r] = a;
    M[r] = 0.f;
  }

  const float pl = s_plen[lb];
  for (int t = 0; t < 16; ++t) {
    const float op = s_prog[lb][t * 5 + 0];
    const float dst = s_prog[lb][t * 5 + 1];
    const float sa = s_prog[lb][t * 5 + 2];
    const float sb = s_prog[lb][t * 5 + 3];
    const float imm = s_prog[lb][t * 5 + 4];
    const float active = fminf(fmaxf(pl - (float)t, 0.f), 1.f);
    float r1 = 0.f, r2 = 0.f, m1 = 0.f, old = 0.f;
    float wd[8];
#pragma unroll
    for (int i = 0; i < 8; ++i) {
      const float w1 = fmaxf(1.f - fabsf(sa - (float)i), 0.f);
      const float w2 = fmaxf(1.f - fabsf(sb - (float)i), 0.f);
      wd[i] = fmaxf(1.f - fabsf(dst - (float)i), 0.f);
      r1 = fmaf(w1, R[i], r1);
      r2 = fmaf(w2, R[i], r2);
      m1 = fmaf(w1, M[i], m1);
      old = fmaf(wd[i], R[i], old);
    }
    float results[16];
    results[0] = old;               results[1] = r1 + r2;
    results[2] = r1 - r2;           results[3] = r1 * r2 * (1.f / 65536.f);
    results[4] = r1;                results[5] = imm;
    results[6] = r1 + imm;          results[7] = fmaxf(r1, r2);
    results[8] = fminf(r1, r2);     results[9] = -r1;
    results[10] = 0.5f * r1;        results[11] = r2;
    results[12] = m1;               results[13] = old;
    results[14] = fabsf(r1);        results[15] = old;
    float res = 0.f;
    const float pstore = fmaxf(1.f - fabsf(op - 13.f), 0.f);
#pragma unroll
    for (int o = 0; o < 16; ++o) res = fmaf(fmaxf(1.f - fabsf(op - (float)o), 0.f), results[o], res);
#pragma unroll
    for (int i = 0; i < 8; ++i) {
      R[i] = fmaf(active * wd[i], res - R[i], R[i]);
      M[i] = fmaf(active * pstore * wd[i], r1 - M[i], M[i]);
    }
  }

  float* outp = Rfinal + (size_t)bg * 8;
#pragma unroll
  for (int r = 0; r < 8; ++r) outp[r] = R[r];
}

// ---------------- expand: W fragment in registers, each wave loops 32 rows ----------------
__global__ __launch_bounds__(256) void final_expand2(const float* __restrict__ Rf,
                                                     const float* __restrict__ W,
                                                     const float* __restrict__ bias,
                                                     const float* __restrict__ gam,
                                                     const float* __restrict__ bet,
                                                     float* __restrict__ out, int rowsPerWave) {
  const int lane = threadIdx.x & 63;
  const int w = blockIdx.x * 4 + (threadIdx.x >> 6);
  const int h0 = lane * 8;

  float wreg[8][8];
#pragma unroll
  for (int reg = 0; reg < 8; ++reg) {
    const float4 wa = *reinterpret_cast<const float4*>(&W[reg * 512 + h0]);
    const float4 wb = *reinterpret_cast<const float4*>(&W[reg * 512 + h0 + 4]);
    wreg[reg][0] = wa.x; wreg[reg][1] = wa.y; wreg[reg][2] = wa.z; wreg[reg][3] = wa.w;
    wreg[reg][4] = wb.x; wreg[reg][5] = wb.y; wreg[reg][6] = wb.z; wreg[reg][7] = wb.w;
  }
  float bi[8], ga[8], be[8];
  {
    const float4 a = *reinterpret_cast<const float4*>(&bias[h0]);
    const float4 b = *reinterpret_cast<const float4*>(&bias[h0 + 4]);
    bi[0] = a.x; bi[1] = a.y; bi[2] = a.z; bi[3] = a.w; bi[4] = b.x; bi[5] = b.y; bi[6] = b.z; bi[7] = b.w;
    const float4 c = *reinterpret_cast<const float4*>(&gam[h0]);
    const float4 d = *reinterpret_cast<const float4*>(&gam[h0 + 4]);
    ga[0] = c.x; ga[1] = c.y; ga[2] = c.z; ga[3] = c.w; ga[4] = d.x; ga[5] = d.y; ga[6] = d.z; ga[7] = d.w;
    const float4 e = *reinterpret_cast<const float4*>(&bet[h0]);
    const float4 f = *reinterpret_cast<const float4*>(&bet[h0 + 4]);
    be[0] = e.x; be[1] = e.y; be[2] = e.z; be[3] = e.w; be[4] = f.x; be[5] = f.y; be[6] = f.z; be[7] = f.w;
  }

  const int r0 = w * rowsPerWave;
  for (int i = 0; i < rowsPerWave; ++i) {
    const int row = r0 + i;
    const float4 ra = *reinterpret_cast<const float4*>(&Rf[(size_t)row * 8]);
    const float4 rb = *reinterpret_cast<const float4*>(&Rf[(size_t)row * 8 + 4]);
    const float r[8] = {ra.x, ra.y, ra.z, ra.w, rb.x, rb.y, rb.z, rb.w};
    float x[8];
#pragma unroll
    for (int j = 0; j < 8; ++j) x[j] = bi[j];
#pragma unroll
    for (int reg = 0; reg < 8; ++reg)
#pragma unroll
      for (int j = 0; j < 8; ++j) x[j] = fmaf(r[reg], wreg[reg][j], x[j]);
    float s1 = 0.f, s2 = 0.f;
#pragma unroll
    for (int j = 0; j < 8; ++j) { s1 += x[j]; s2 = fmaf(x[j], x[j], s2); }
#pragma unroll
    for (int off = 32; off; off >>= 1) { s1 += __shfl_xor(s1, off); s2 += __shfl_xor(s2, off); }
    const float mean = s1 * (1.f / 512.f);
    const float var = s2 * (1.f / 512.f) - mean * mean;
    const float inv = rsqrtf(var + 1e-5f);
    float y[8];
#pragma unroll
    for (int j = 0; j < 8; ++j) y[j] = (x[j] - mean) * inv * ga[j] + be[j];
    float* dst = out + (size_t)row * 512 + h0;
    *reinterpret_cast<float4*>(dst) = make_float4(y[0], y[1], y[2], y[3]);
    *reinterpret_cast<float4*>(dst + 4) = make_float4(y[4], y[5], y[6], y[7]);
  }
}

// ---------------- launch ----------------
extern "C" void kernel_launch(void* const* d_in, const int* in_sizes, int n_in,
                              void* d_out, int out_size, void* d_ws, size_t ws_size,
                              hipStream_t stream) {
  const float* z    = (const float*)d_in[0];
  const float* P_op = (const float*)d_in[1];
  const float* P_dst= (const float*)d_in[2];
  const float* P_s1 = (const float*)d_in[3];
  const float* P_s2 = (const float*)d_in[4];
  const float* P_imm= (const float*)d_in[5];
  const float* Plen = (const float*)d_in[6];
  const float* W1   = (const float*)d_in[8];
  const float* b1   = (const float*)d_in[9];
  const float* WR   = (const float*)d_in[10];
  const float* bR   = (const float*)d_in[11];
  const float* Wt   = (const float*)d_in[12];
  const float* bt   = (const float*)d_in[13];
  const float* W_r2h= (const float*)d_in[14];
  const float* b_r2h= (const float*)d_in[15];
  const float* ln_g = (const float*)d_in[16];
  const float* ln_b = (const float*)d_in[17];

  const int B = in_sizes[0] / 512;  // 8192
  float* out = (float*)d_out;
  float* part    = out + (size_t)(1 << 25);            // 8 * B*128 f32 K-split partials (read before expand writes)
  float* thr_out = out + (size_t)B * 16 * 512;         // threshold output region

  float* ws = (float*)d_ws;
  float* prog   = ws;                                  // B*16*5
  float* plen   = prog + (size_t)B * 80;               // B
  float* Rfinal = plen + B;                            // B*16*8
  float* thr_part = Rfinal + (size_t)B * 128;          // 8 * B
  unsigned short* W1t = (unsigned short*)(thr_part + (size_t)8 * B);  // 1024x512 bf16
  unsigned short* WRt = W1t + (size_t)1024 * 512;                     // 128x1024 bf16
  unsigned short* zb  = WRt + (size_t)128 * 1024;                     // B*512 bf16

  const dim3 blk(256);
  prep_kernel<<<dim3(3200), blk, 0, stream>>>(z, zb, B * 512 / 8, W1, WR, W1t, WRt,
                                              P_op, P_dst, P_s1, P_s2, P_imm, Plen,
                                              prog, plen, B * 16);
  gemm_fused<<<dim3(8, B / 128), blk, 0, stream>>>(zb, W1t, b1, WRt, Wt, part, thr_part, B);
  scan2_kernel<<<dim3(B / 16), blk, 0, stream>>>(part, bR, thr_part, bt, prog, plen, Rfinal,
                                                 thr_out, B);
  final_expand2<<<dim3(B * 16 / 4 / 32), blk, 0, stream>>>(Rfinal, W_r2h, b_r2h, ln_g, ln_b, out,
                                                           32);
}